// Round 10
// baseline (5956.977 us; speedup 1.0000x reference)
//
#include <hip/hip_runtime.h>
#include <math.h>

#define NHID 8
#define NHEADS 8
#define EMB 64
#define NPROT 2048
#define NDRUG 1500
#define NPAIR 16384

typedef _Float16 h2 __attribute__((ext_vector_type(2)));

// ---------------- GAT: Wh[h][n][o] = sum_f h[n,f] * W[h,f,o] ----------------
__global__ void k_gat_wh(const float* __restrict__ h, const float* __restrict__ W,
                         float* __restrict__ Wh, int N, int F) {
    int idx = blockIdx.x * 256 + threadIdx.x;       // flat (hh, n, o)
    int total = NHEADS * N * NHID;
    if (idx >= total) return;
    int o  = idx & 7;
    int n  = (idx >> 3) % N;
    int hh = idx / (N * 8);
    const float4* hp4 = (const float4*)(h + (size_t)n * F);
    const float* wp = W + (size_t)hh * F * 8 + o;
    float acc = 0.f;
    for (int f4 = 0; f4 < (F >> 2); ++f4) {
        float4 hv = hp4[f4];
        int fb = f4 * 32;                            // (f4*4)*8
        acc = fmaf(hv.x, wp[fb], fmaf(hv.y, wp[fb + 8],
              fmaf(hv.z, wp[fb + 16], fmaf(hv.w, wp[fb + 24], acc))));
    }
    Wh[idx] = acc;
}

// s1[h][n] = Wh[h][n][:] . a[h][:8];  s2 uses a[h][8:16]
__global__ void k_gat_s(const float* __restrict__ Wh, const float* __restrict__ a,
                        float* __restrict__ s1, float* __restrict__ s2, int N) {
    int idx = blockIdx.x * 256 + threadIdx.x;       // h*N + n
    if (idx >= NHEADS * N) return;
    int hh = idx / N;
    const float* wp = Wh + (size_t)idx * 8;
    const float* ap = a + hh * 16;
    float x1 = 0.f, x2 = 0.f;
    for (int o = 0; o < 8; ++o) { x1 += wp[o] * ap[o]; x2 += wp[o] * ap[8 + o]; }
    s1[idx] = x1; s2[idx] = x2;
}

// One block per row i. 8 concurrent head-groups of 32 lanes each.
__global__ void k_gat_attn(const float* __restrict__ adj, const float* __restrict__ s1,
                           const float* __restrict__ s2, const float* __restrict__ Wh,
                           float* __restrict__ out, int N) {
    __shared__ int nbr[2048];
    __shared__ int s_cnt;
    int i = blockIdx.x;
    int tid = threadIdx.x;
    if (tid == 0) s_cnt = 0;
    __syncthreads();
    const float* arow = adj + (size_t)i * N;
    for (int j = tid; j < N; j += 256)
        if (arow[j] > 0.f) { int p = atomicAdd(&s_cnt, 1); nbr[p] = j; }
    __syncthreads();
    int cnt = s_cnt;
    int g  = tid >> 5;          // head index 0..7
    int ln = tid & 31;          // lane within head-group
    float si = s1[g * N + i];
    const float* s2h = s2 + g * N;
    // pass 1: group max of leakyrelu(si + s2[j])
    float mx = -1e30f;
    for (int t = ln; t < cnt; t += 32) {
        float e = si + s2h[nbr[t]];
        e = e > 0.f ? e : 0.2f * e;
        mx = fmaxf(mx, e);
    }
    #pragma unroll
    for (int off = 16; off; off >>= 1) mx = fmaxf(mx, __shfl_xor(mx, off, 32));
    // pass 2: exp-sum + weighted accumulation of Wh rows
    float acc[8] = {0, 0, 0, 0, 0, 0, 0, 0};
    float lsum = 0.f;
    for (int t = ln; t < cnt; t += 32) {
        int j = nbr[t];
        float e = si + s2h[j];
        e = e > 0.f ? e : 0.2f * e;
        float p = __expf(e - mx);
        lsum += p;
        const float4* wp = (const float4*)(Wh + ((size_t)g * N + j) * 8);
        float4 w0 = wp[0], w1 = wp[1];
        acc[0] += p * w0.x; acc[1] += p * w0.y; acc[2] += p * w0.z; acc[3] += p * w0.w;
        acc[4] += p * w1.x; acc[5] += p * w1.y; acc[6] += p * w1.z; acc[7] += p * w1.w;
    }
    #pragma unroll
    for (int off = 16; off; off >>= 1) {
        lsum += __shfl_xor(lsum, off, 32);
        #pragma unroll
        for (int d = 0; d < 8; ++d) acc[d] += __shfl_xor(acc[d], off, 32);
    }
    if (ln == 0) {
        float inv = 1.f / lsum;
        #pragma unroll
        for (int d = 0; d < 8; ++d) {
            float r = acc[d] * inv;
            out[(size_t)i * 64 + g * 8 + d] = r > 0.f ? r : 0.f;   // relu
        }
    }
}

// out[n][o] = sum_d in[n][d] * W[o][d]   (x @ W.T, no bias)
__global__ void k_proj(const float* __restrict__ in, const float* __restrict__ W,
                       float* __restrict__ out, int N) {
    int idx = blockIdx.x * 256 + threadIdx.x;
    if (idx >= N * 64) return;
    int o = idx & 63, n = idx >> 6;
    const float* ip = in + (size_t)n * 64;
    const float* wp = W + (size_t)o * 64;
    float acc = 0.f;
    for (int d = 0; d < 64; ++d) acc += ip[d] * wp[d];
    out[idx] = acc;
}

// qkv layout: [sm][h][n][8]  (slice per (module,head) contiguous)
__global__ void k_qkv(const float* __restrict__ x, const float* __restrict__ W,
                      const float* __restrict__ b, float* __restrict__ qkv, int N) {
    int idx = blockIdx.x * 256 + threadIdx.x;
    int total = 24 * N * 64;
    if (idx >= total) return;
    int o = idx & 63;
    int n = (idx >> 6) % N;
    int sm = idx / (N * 64);
    const float4* xp4 = (const float4*)(x + (size_t)n * 64);
    const float4* wp4 = (const float4*)(W + ((size_t)sm * 64 + o) * 64);
    float acc = b[sm * 64 + o];
    #pragma unroll 4
    for (int d4 = 0; d4 < 16; ++d4) {
        float4 xv = xp4[d4], wv = wp4[d4];
        acc = fmaf(xv.x, wv.x, fmaf(xv.y, wv.y, fmaf(xv.z, wv.z, fmaf(xv.w, wv.w, acc))));
    }
    qkv[(size_t)sm * N * 64 + (size_t)(o >> 3) * N * 8 + (size_t)n * 8 + (o & 7)] = acc;
}

// ---------------- MHSA flash attention, hd=8, fp16 QK via v_dot2 ----------------
// Lane = j; wave owns 8 q-rows. Q,K packed fp16 (halves regs + score ops);
// V,acc stay f32. LDS tile [64 j][4 float4-slots]: slot0 = K(8 fp16),
// slot1/2 = V f32, slot-swizzled. No-max exp2 softmax (qs folds 1/sqrt(8)*log2e).
#define QLOADH(qa, qb, qc, qd, r) { int row_ = row0 + (r); if (row_ >= N) row_ = 0; \
    const float4* qp_ = (const float4*)(qsl + (size_t)row_ * 8);                  \
    float4 a_ = qp_[0], b_ = qp_[1];                                              \
    qa = h2{(_Float16)(a_.x * qs), (_Float16)(a_.y * qs)};                        \
    qb = h2{(_Float16)(a_.z * qs), (_Float16)(a_.w * qs)};                        \
    qc = h2{(_Float16)(b_.x * qs), (_Float16)(b_.y * qs)};                        \
    qd = h2{(_Float16)(b_.z * qs), (_Float16)(b_.w * qs)}; }

#define ROWSTEPH(qa, qb, qc, qd, ca, cb, lr) {                                    \
    float s_ = __builtin_amdgcn_fdot2(qa, kk0,                                    \
               __builtin_amdgcn_fdot2(qb, kk1,                                    \
               __builtin_amdgcn_fdot2(qc, kk2,                                    \
               __builtin_amdgcn_fdot2(qd, kk3, 0.f, false), false), false), false);\
    float p_ = exp2f(s_); lr += p_;                                               \
    ca.x = fmaf(p_, vv0.x, ca.x); ca.y = fmaf(p_, vv0.y, ca.y);                   \
    ca.z = fmaf(p_, vv0.z, ca.z); ca.w = fmaf(p_, vv0.w, ca.w);                   \
    cb.x = fmaf(p_, vv1.x, cb.x); cb.y = fmaf(p_, vv1.y, cb.y);                   \
    cb.z = fmaf(p_, vv1.z, cb.z); cb.w = fmaf(p_, vv1.w, cb.w); }

#define BF3A(v) { v += __shfl_xor(v, 1, 64); v += __shfl_xor(v, 2, 64);           \
                  v += __shfl_xor(v, 4, 64); }

#define ROWOUT(ca, cb, lr, r) {                                                   \
    BF3A(ca.x); BF3A(ca.y); BF3A(ca.z); BF3A(ca.w);                               \
    BF3A(cb.x); BF3A(cb.y); BF3A(cb.z); BF3A(cb.w); BF3A(lr);                     \
    int sel_ = ln & 7;                                                            \
    float t_ = (sel_ == 0) ? ca.x : (sel_ == 1) ? ca.y : (sel_ == 2) ? ca.z :     \
               (sel_ == 3) ? ca.w : (sel_ == 4) ? cb.x : (sel_ == 5) ? cb.y :     \
               (sel_ == 6) ? cb.z : cb.w;                                         \
    t_ += __shfl_xor(t_, 8, 64); t_ += __shfl_xor(t_, 16, 64);                    \
    t_ += __shfl_xor(t_, 32, 64);                                                 \
    lr += __shfl_xor(lr, 8, 64); lr += __shfl_xor(lr, 16, 64);                    \
    lr += __shfl_xor(lr, 32, 64);                                                 \
    int row_ = row0 + (r);                                                        \
    if (ln < 8 && row_ < N)                                                       \
        atomicAdd(&accum[(size_t)row_ * 64 + hh * 8 + ln], t_ / (lr - phantom)); }

__global__ __launch_bounds__(256, 6)
void k_attn(const float* __restrict__ qkv, float* __restrict__ accum, int N) {
    __shared__ float4 kvt[256];            // [64 j][4 slots], slot-swizzled
    int bid = blockIdx.x;
    int m  = bid & 7;                      // same m -> same XCD (L2 locality)
    int hh = (bid >> 3) & 7;
    int rt = bid >> 6;
    int wid = threadIdx.x >> 6, ln = threadIdx.x & 63;
    int row0 = rt * 32 + wid * 8;
    const float* qsl = qkv + (size_t)m        * N * 64 + (size_t)hh * N * 8;
    const float* ksl = qkv + (size_t)(8 + m)  * N * 64 + (size_t)hh * N * 8;
    const float* vsl = qkv + (size_t)(16 + m) * N * 64 + (size_t)hh * N * 8;

    const float qs = 0.35355339059327373f * 1.44269504088896341f;  // 1/sqrt(8)*log2(e)
    h2 q0a, q0b, q0c, q0d, q1a, q1b, q1c, q1d, q2a, q2b, q2c, q2d, q3a, q3b, q3c, q3d;
    h2 q4a, q4b, q4c, q4d, q5a, q5b, q5c, q5d, q6a, q6b, q6c, q6d, q7a, q7b, q7c, q7d;
    QLOADH(q0a, q0b, q0c, q0d, 0) QLOADH(q1a, q1b, q1c, q1d, 1)
    QLOADH(q2a, q2b, q2c, q2d, 2) QLOADH(q3a, q3b, q3c, q3d, 3)
    QLOADH(q4a, q4b, q4c, q4d, 4) QLOADH(q5a, q5b, q5c, q5d, 5)
    QLOADH(q6a, q6b, q6c, q6d, 6) QLOADH(q7a, q7b, q7c, q7d, 7)

    // staging roles per j (4 threads): part0 = K lo (cvt fp16), part3 = K hi,
    // part1 = V lo (f32), part2 = V hi
    int sj = threadIdx.x >> 2;
    int part = threadIdx.x & 3;
    bool isK = (part == 0) | (part == 3);
    const float* sb = isK ? ksl : vsl;
    int halfo = (part & 2) ? 4 : 0;        // part2/part3 take floats 4-7
    int slot_base = isK ? 0 : (part == 1 ? 1 : 2);
    int slot = slot_base ^ ((sj >> 1) & 3);
    float4* vdst = &kvt[sj * 4 + slot];
    float2* kdst = (float2*)((char*)&kvt[sj * 4 + slot] + ((part == 3) ? 8 : 0));

    int Tt = (N + 63) >> 6;
    float4 pre = (sj < N) ? *(const float4*)(sb + (size_t)sj * 8 + halfo)
                          : make_float4(0.f, 0.f, 0.f, 0.f);

    float l0 = 0.f, l1 = 0.f, l2 = 0.f, l3 = 0.f, l4 = 0.f, l5 = 0.f, l6 = 0.f, l7 = 0.f;
    float4 z4 = make_float4(0.f, 0.f, 0.f, 0.f);
    float4 c0a = z4, c0b = z4, c1a = z4, c1b = z4, c2a = z4, c2b = z4, c3a = z4, c3b = z4;
    float4 c4a = z4, c4b = z4, c5a = z4, c5b = z4, c6a = z4, c6b = z4, c7a = z4, c7b = z4;

    int sw = (ln >> 1) & 3;
    const float4* rbase = &kvt[ln * 4];

    for (int t = 0; t < Tt; ++t) {
        __syncthreads();                   // previous tile fully consumed
        if (isK) {
            h2 lo = h2{(_Float16)pre.x, (_Float16)pre.y};
            h2 hi = h2{(_Float16)pre.z, (_Float16)pre.w};
            float2 st;
            st.x = __builtin_bit_cast(float, lo);
            st.y = __builtin_bit_cast(float, hi);
            *kdst = st;
        } else {
            *vdst = pre;
        }
        __syncthreads();                   // tile ready
        if (t + 1 < Tt) {
            int j = (t + 1) * 64 + sj;
            pre = (j < N) ? *(const float4*)(sb + (size_t)j * 8 + halfo)
                          : make_float4(0.f, 0.f, 0.f, 0.f);
        }
        float4 kf = rbase[0 ^ sw];
        h2 kk0 = __builtin_bit_cast(h2, kf.x);
        h2 kk1 = __builtin_bit_cast(h2, kf.y);
        h2 kk2 = __builtin_bit_cast(h2, kf.z);
        h2 kk3 = __builtin_bit_cast(h2, kf.w);
        float4 vv0 = rbase[1 ^ sw], vv1 = rbase[2 ^ sw];
        ROWSTEPH(q0a, q0b, q0c, q0d, c0a, c0b, l0)
        ROWSTEPH(q1a, q1b, q1c, q1d, c1a, c1b, l1)
        ROWSTEPH(q2a, q2b, q2c, q2d, c2a, c2b, l2)
        ROWSTEPH(q3a, q3b, q3c, q3d, c3a, c3b, l3)
        ROWSTEPH(q4a, q4b, q4c, q4d, c4a, c4b, l4)
        ROWSTEPH(q5a, q5b, q5c, q5d, c5a, c5b, l5)
        ROWSTEPH(q6a, q6b, q6c, q6d, c6a, c6b, l6)
        ROWSTEPH(q7a, q7b, q7c, q7d, c7a, c7b, l7)
    }

    float phantom = (float)(Tt * 64 - N);  // zero-staged tails contribute exp2(0)=1
    ROWOUT(c0a, c0b, l0, 0) ROWOUT(c1a, c1b, l1, 1)
    ROWOUT(c2a, c2b, l2, 2) ROWOUT(c3a, c3b, l3, 3)
    ROWOUT(c4a, c4b, l4, 4) ROWOUT(c5a, c5b, l5, 5)
    ROWOUT(c6a, c6b, l6, 6) ROWOUT(c7a, c7b, l7, 7)
}

// out = LN(acc + resid) * g + b ; one wave (64 lanes) per row
__global__ void k_ln(const float* __restrict__ acc, const float* __restrict__ resid,
                     const float* __restrict__ g, const float* __restrict__ b,
                     float* __restrict__ out, int N) {
    int r = blockIdx.x * 4 + (threadIdx.x >> 6);
    int d = threadIdx.x & 63;
    if (r >= N) return;
    float v = acc[(size_t)r * 64 + d] + resid[(size_t)r * 64 + d];
    float s = v;
    for (int off = 32; off; off >>= 1) s += __shfl_xor(s, off, 64);
    float mean = s * (1.f / 64.f);
    float c = v - mean;
    float vv = c * c;
    for (int off = 32; off; off >>= 1) vv += __shfl_xor(vv, off, 64);
    float var = vv * (1.f / 64.f);
    out[(size_t)r * 64 + d] = c * rsqrtf(var + 1e-5f) * g[d] + b[d];
}

// ---------------- Final MLP: LDS-tiled 3-layer GEMM ----------------
#define MLP_STEP(ai, xi) {                                                        \
    ai.x = fmaf(xi.x, w0.x, fmaf(xi.y, w0.y, fmaf(xi.z, w0.z, fmaf(xi.w, w0.w, ai.x)))); \
    ai.y = fmaf(xi.x, w1.x, fmaf(xi.y, w1.y, fmaf(xi.z, w1.z, fmaf(xi.w, w1.w, ai.y)))); \
    ai.z = fmaf(xi.x, w2.x, fmaf(xi.y, w2.y, fmaf(xi.z, w2.z, fmaf(xi.w, w2.w, ai.z)))); \
    ai.w = fmaf(xi.x, w3.x, fmaf(xi.y, w3.y, fmaf(xi.z, w3.z, fmaf(xi.w, w3.w, ai.w)))); }

#define MLP_LAYER(B_)                                                             \
    a0 = z4; a1 = z4; a2 = z4; a3 = z4; a4 = z4; a5 = z4; a6 = z4; a7 = z4;       \
    _Pragma("unroll 4")                                                           \
    for (int k4 = 0; k4 < 32; ++k4) {                                             \
        float4 w0 = sW4[og][k4 ^ swz];                                            \
        float4 w1 = sW4[og + 32][k4 ^ swz];                                       \
        float4 w2 = sW4[og + 64][k4 ^ swz];                                       \
        float4 w3 = sW4[og + 96][k4 ^ swz];                                       \
        float4 x0 = sX4[pb + 0][k4], x1 = sX4[pb + 1][k4];                        \
        float4 x2 = sX4[pb + 2][k4], x3 = sX4[pb + 3][k4];                        \
        float4 x4 = sX4[pb + 4][k4], x5 = sX4[pb + 5][k4];                        \
        float4 x6 = sX4[pb + 6][k4], x7 = sX4[pb + 7][k4];                        \
        MLP_STEP(a0, x0) MLP_STEP(a1, x1) MLP_STEP(a2, x2) MLP_STEP(a3, x3)       \
        MLP_STEP(a4, x4) MLP_STEP(a5, x5) MLP_STEP(a6, x6) MLP_STEP(a7, x7)       \
    }                                                                             \
    {                                                                             \
        float bo0 = B_[og], bo1 = B_[og + 32], bo2 = B_[og + 64], bo3 = B_[og + 96]; \
        a0.x += bo0; a0.y += bo1; a0.z += bo2; a0.w += bo3;                       \
        a1.x += bo0; a1.y += bo1; a1.z += bo2; a1.w += bo3;                       \
        a2.x += bo0; a2.y += bo1; a2.z += bo2; a2.w += bo3;                       \
        a3.x += bo0; a3.y += bo1; a3.z += bo2; a3.w += bo3;                       \
        a4.x += bo0; a4.y += bo1; a4.z += bo2; a4.w += bo3;                       \
        a5.x += bo0; a5.y += bo1; a5.z += bo2; a5.w += bo3;                       \
        a6.x += bo0; a6.y += bo1; a6.z += bo2; a6.w += bo3;                       \
        a7.x += bo0; a7.y += bo1; a7.z += bo2; a7.w += bo3;                       \
    }

#define MLP_HWRITE(ai, i) {                                                       \
    float* hp_ = sXf + (size_t)(pb + (i)) * 128;                                  \
    hp_[og]      = ai.x > 0.f ? ai.x : 0.f;                                       \
    hp_[og + 32] = ai.y > 0.f ? ai.y : 0.f;                                       \
    hp_[og + 64] = ai.z > 0.f ? ai.z : 0.f;                                       \
    hp_[og + 96] = ai.w > 0.f ? ai.w : 0.f; }

#define MLP_WLOAD(Wg_) {                                                          \
    const float4* wsrc_ = (const float4*)(Wg_);                                   \
    _Pragma("unroll")                                                             \
    for (int u = 0; u < 16; ++u) {                                                \
        int f4 = u * 256 + t;                                                     \
        int o_ = f4 >> 5, k4_ = f4 & 31;                                          \
        sW4[o_][k4_ ^ (o_ & 7)] = wsrc_[f4];                                      \
    } }

__global__ __launch_bounds__(256, 1)
void k_mlp(const float* __restrict__ px, const float* __restrict__ dx,
           const int* __restrict__ pairs,
           const float* __restrict__ W1, const float* __restrict__ b1,
           const float* __restrict__ W2, const float* __restrict__ b2,
           const float* __restrict__ W3, const float* __restrict__ b3,
           float* __restrict__ out) {
    __shared__ float4 sX4[64][32];         // 32 KB: x tile, then h1, then h2
    __shared__ float4 sW4[128][32];        // 64 KB: W1, then W2 (swizzled)
    float* sXf = (float*)sX4;
    int t = threadIdx.x;
    int base = blockIdx.x * 64;

    // gather X = concat(px[ip], dx[id]) for 64 pairs
    #pragma unroll
    for (int u = 0; u < 8; ++u) {
        int idx = u * 256 + t;
        int p = idx >> 5, c4 = idx & 31;
        int ip = pairs[(base + p) * 2], id = pairs[(base + p) * 2 + 1];
        float4 v = (c4 < 16) ? ((const float4*)px)[(size_t)ip * 16 + c4]
                             : ((const float4*)dx)[(size_t)id * 16 + (c4 - 16)];
        sX4[p][c4] = v;
    }
    MLP_WLOAD(W1)
    __syncthreads();

    int og = t & 31;                       // out group: o = og + 32j
    int pb = (t >> 5) * 8;                 // first of 8 pairs
    int swz = og & 7;                      // W k4-swizzle (32j keeps o&7 = og&7)
    float4 z4 = make_float4(0.f, 0.f, 0.f, 0.f);
    float4 a0, a1, a2, a3, a4, a5, a6, a7;

    MLP_LAYER(b1)                          // fc1 from X
    __syncthreads();                       // all fc1 reads done
    MLP_HWRITE(a0, 0) MLP_HWRITE(a1, 1) MLP_HWRITE(a2, 2) MLP_HWRITE(a3, 3)
    MLP_HWRITE(a4, 4) MLP_HWRITE(a5, 5) MLP_HWRITE(a6, 6) MLP_HWRITE(a7, 7)
    MLP_WLOAD(W2)
    __syncthreads();                       // h1 + W2 ready

    MLP_LAYER(b2)                          // fc2 from h1
    __syncthreads();                       // all fc2 reads done
    MLP_HWRITE(a0, 0) MLP_HWRITE(a1, 1) MLP_HWRITE(a2, 2) MLP_HWRITE(a3, 3)
    MLP_HWRITE(a4, 4) MLP_HWRITE(a5, 5) MLP_HWRITE(a6, 6) MLP_HWRITE(a7, 7)
    __syncthreads();                       // h2 ready

    // fc3: out[p] = b3 + h2[p] . W3   (4 threads per pair, shfl-reduce)
    {
        int p = t >> 2, qd = t & 3;
        const float4* w3 = (const float4*)W3;
        float sum = 0.f;
        #pragma unroll
        for (int u = 0; u < 8; ++u) {
            float4 h = sX4[p][qd * 8 + u];
            float4 w = w3[qd * 8 + u];
            sum += h.x * w.x + h.y * w.y + h.z * w.z + h.w * w.w;
        }
        sum += __shfl_xor(sum, 1, 64);
        sum += __shfl_xor(sum, 2, 64);
        if ((t & 3) == 0) out[base + p] = sum + b3[0];
    }
}

extern "C" void kernel_launch(void* const* d_in, const int* in_sizes, int n_in,
                              void* d_out, int out_size, void* d_ws, size_t ws_size,
                              hipStream_t stream) {
    const float* pfeat = (const float*)d_in[0];
    const float* padj  = (const float*)d_in[1];
    const float* dfeat = (const float*)d_in[2];
    const float* dadj  = (const float*)d_in[3];
    const int*   pairs = (const int*)d_in[4];
    const float* fc1W = (const float*)d_in[33];
    const float* fc1b = (const float*)d_in[34];
    const float* fc2W = (const float*)d_in[35];
    const float* fc2b = (const float*)d_in[36];
    const float* fc3W = (const float*)d_in[37];
    const float* fc3b = (const float*)d_in[38];

    float* ws = (float*)d_ws;
    float* buf_Wh   = ws;                              // 8*2048*8   = 131072
    float* buf_s1   = buf_Wh   + 8 * 2048 * 8;         // 16384
    float* buf_s2   = buf_s1   + 8 * 2048;             // 16384
    float* buf_gat  = buf_s2   + 8 * 2048;             // 131072
    float* buf_proj = buf_gat  + 2048 * 64;            // 131072
    float* buf_qkv  = buf_proj + 2048 * 64;            // 3145728
    float* buf_acc  = buf_qkv  + 24 * 2048 * 64;       // 131072
    float* buf_x    = buf_acc  + 2048 * 64;            // 131072
    float* buf_px   = buf_x    + 2048 * 64;            // 131072
    float* buf_dx   = buf_px   + 2048 * 64;            // 96000

    auto run_branch = [&](const float* feat, const float* adj, int N, int F,
                          void* const* w, float* xout) {
        const float* g1W = (const float*)w[0];
        const float* g1a = (const float*)w[1];
        const float* p1W = (const float*)w[2];
        const float* s1W = (const float*)w[3];
        const float* s1b = (const float*)w[4];
        const float* l1g = (const float*)w[5];
        const float* l1b = (const float*)w[6];
        const float* g2W = (const float*)w[7];
        const float* g2a = (const float*)w[8];
        const float* p2W = (const float*)w[9];
        const float* s2W = (const float*)w[10];
        const float* s2b = (const float*)w[11];
        const float* l2g = (const float*)w[12];
        const float* l2b = (const float*)w[13];

        int attnGrid = 64 * ((N + 31) / 32);   // bid: m=bid&7, h=(bid>>3)&7, rt=bid>>6

        // ---- layer 1 ----
        k_gat_wh<<<(64 * N + 255) / 256, 256, 0, stream>>>(feat, g1W, buf_Wh, N, F);
        k_gat_s<<<(8 * N + 255) / 256, 256, 0, stream>>>(buf_Wh, g1a, buf_s1, buf_s2, N);
        k_gat_attn<<<N, 256, 0, stream>>>(adj, buf_s1, buf_s2, buf_Wh, buf_gat, N);
        k_proj<<<(64 * N + 255) / 256, 256, 0, stream>>>(buf_gat, p1W, buf_proj, N);
        k_qkv<<<(1536 * N + 255) / 256, 256, 0, stream>>>(buf_proj, s1W, s1b, buf_qkv, N);
        hipMemsetAsync(buf_acc, 0, (size_t)N * 64 * sizeof(float), stream);
        k_attn<<<attnGrid, 256, 0, stream>>>(buf_qkv, buf_acc, N);
        k_ln<<<(N + 3) / 4, 256, 0, stream>>>(buf_acc, buf_proj, l1g, l1b, buf_x, N);
        // ---- layer 2 ----
        k_gat_wh<<<(64 * N + 255) / 256, 256, 0, stream>>>(buf_x, g2W, buf_Wh, N, EMB);
        k_gat_s<<<(8 * N + 255) / 256, 256, 0, stream>>>(buf_Wh, g2a, buf_s1, buf_s2, N);
        k_gat_attn<<<N, 256, 0, stream>>>(adj, buf_s1, buf_s2, buf_Wh, buf_gat, N);
        k_proj<<<(64 * N + 255) / 256, 256, 0, stream>>>(buf_gat, p2W, buf_proj, N);
        k_qkv<<<(1536 * N + 255) / 256, 256, 0, stream>>>(buf_proj, s2W, s2b, buf_qkv, N);
        hipMemsetAsync(buf_acc, 0, (size_t)N * 64 * sizeof(float), stream);
        k_attn<<<attnGrid, 256, 0, stream>>>(buf_qkv, buf_acc, N);
        k_ln<<<(N + 3) / 4, 256, 0, stream>>>(buf_acc, buf_proj, l2g, l2b, xout, N);
    };

    run_branch(pfeat, padj, NPROT, 512, d_in + 5, buf_px);
    run_branch(dfeat, dadj, NDRUG, 256, d_in + 19, buf_dx);

    k_mlp<<<NPAIR / 64, 256, 0, stream>>>(buf_px, buf_dx, pairs,
                                          fc1W, fc1b, fc2W, fc2b, fc3W, fc3b,
                                          (float*)d_out);
}

// Round 13
// 1536.494 us; speedup vs baseline: 3.8770x; 3.8770x over previous
//
#include <hip/hip_runtime.h>
#include <math.h>

#define NHID 8
#define NHEADS 8
#define EMB 64
#define NPROT 2048
#define NDRUG 1500
#define NPAIR 16384

typedef _Float16 h2 __attribute__((ext_vector_type(2)));

// ---------------- GAT: Wh[h][n][o] = sum_f h[n,f] * W[h,f,o] ----------------
__global__ void k_gat_wh(const float* __restrict__ h, const float* __restrict__ W,
                         float* __restrict__ Wh, int N, int F) {
    int idx = blockIdx.x * 256 + threadIdx.x;       // flat (hh, n, o)
    int total = NHEADS * N * NHID;
    if (idx >= total) return;
    int o  = idx & 7;
    int n  = (idx >> 3) % N;
    int hh = idx / (N * 8);
    const float4* hp4 = (const float4*)(h + (size_t)n * F);
    const float* wp = W + (size_t)hh * F * 8 + o;
    float acc = 0.f;
    for (int f4 = 0; f4 < (F >> 2); ++f4) {
        float4 hv = hp4[f4];
        int fb = f4 * 32;                            // (f4*4)*8
        acc = fmaf(hv.x, wp[fb], fmaf(hv.y, wp[fb + 8],
              fmaf(hv.z, wp[fb + 16], fmaf(hv.w, wp[fb + 24], acc))));
    }
    Wh[idx] = acc;
}

// s1[h][n] = Wh[h][n][:] . a[h][:8];  s2 uses a[h][8:16]
__global__ void k_gat_s(const float* __restrict__ Wh, const float* __restrict__ a,
                        float* __restrict__ s1, float* __restrict__ s2, int N) {
    int idx = blockIdx.x * 256 + threadIdx.x;       // h*N + n
    if (idx >= NHEADS * N) return;
    int hh = idx / N;
    const float* wp = Wh + (size_t)idx * 8;
    const float* ap = a + hh * 16;
    float x1 = 0.f, x2 = 0.f;
    for (int o = 0; o < 8; ++o) { x1 += wp[o] * ap[o]; x2 += wp[o] * ap[8 + o]; }
    s1[idx] = x1; s2[idx] = x2;
}

// One block per row i. 8 concurrent head-groups of 32 lanes each.
__global__ void k_gat_attn(const float* __restrict__ adj, const float* __restrict__ s1,
                           const float* __restrict__ s2, const float* __restrict__ Wh,
                           float* __restrict__ out, int N) {
    __shared__ int nbr[2048];
    __shared__ int s_cnt;
    int i = blockIdx.x;
    int tid = threadIdx.x;
    if (tid == 0) s_cnt = 0;
    __syncthreads();
    const float* arow = adj + (size_t)i * N;
    for (int j = tid; j < N; j += 256)
        if (arow[j] > 0.f) { int p = atomicAdd(&s_cnt, 1); nbr[p] = j; }
    __syncthreads();
    int cnt = s_cnt;
    int g  = tid >> 5;          // head index 0..7
    int ln = tid & 31;          // lane within head-group
    float si = s1[g * N + i];
    const float* s2h = s2 + g * N;
    // pass 1: group max of leakyrelu(si + s2[j])
    float mx = -1e30f;
    for (int t = ln; t < cnt; t += 32) {
        float e = si + s2h[nbr[t]];
        e = e > 0.f ? e : 0.2f * e;
        mx = fmaxf(mx, e);
    }
    #pragma unroll
    for (int off = 16; off; off >>= 1) mx = fmaxf(mx, __shfl_xor(mx, off, 32));
    // pass 2: exp-sum + weighted accumulation of Wh rows
    float acc[8] = {0, 0, 0, 0, 0, 0, 0, 0};
    float lsum = 0.f;
    for (int t = ln; t < cnt; t += 32) {
        int j = nbr[t];
        float e = si + s2h[j];
        e = e > 0.f ? e : 0.2f * e;
        float p = __expf(e - mx);
        lsum += p;
        const float4* wp = (const float4*)(Wh + ((size_t)g * N + j) * 8);
        float4 w0 = wp[0], w1 = wp[1];
        acc[0] += p * w0.x; acc[1] += p * w0.y; acc[2] += p * w0.z; acc[3] += p * w0.w;
        acc[4] += p * w1.x; acc[5] += p * w1.y; acc[6] += p * w1.z; acc[7] += p * w1.w;
    }
    #pragma unroll
    for (int off = 16; off; off >>= 1) {
        lsum += __shfl_xor(lsum, off, 32);
        #pragma unroll
        for (int d = 0; d < 8; ++d) acc[d] += __shfl_xor(acc[d], off, 32);
    }
    if (ln == 0) {
        float inv = 1.f / lsum;
        #pragma unroll
        for (int d = 0; d < 8; ++d) {
            float r = acc[d] * inv;
            out[(size_t)i * 64 + g * 8 + d] = r > 0.f ? r : 0.f;   // relu
        }
    }
}

// out[n][o] = sum_d in[n][d] * W[o][d]   (x @ W.T, no bias)
__global__ void k_proj(const float* __restrict__ in, const float* __restrict__ W,
                       float* __restrict__ out, int N) {
    int idx = blockIdx.x * 256 + threadIdx.x;
    if (idx >= N * 64) return;
    int o = idx & 63, n = idx >> 6;
    const float* ip = in + (size_t)n * 64;
    const float* wp = W + (size_t)o * 64;
    float acc = 0.f;
    for (int d = 0; d < 64; ++d) acc += ip[d] * wp[d];
    out[idx] = acc;
}

// qkv layout: [sm][h][n][8]  (slice per (module,head) contiguous)
__global__ void k_qkv(const float* __restrict__ x, const float* __restrict__ W,
                      const float* __restrict__ b, float* __restrict__ qkv, int N) {
    int idx = blockIdx.x * 256 + threadIdx.x;
    int total = 24 * N * 64;
    if (idx >= total) return;
    int o = idx & 63;
    int n = (idx >> 6) % N;
    int sm = idx / (N * 64);
    const float4* xp4 = (const float4*)(x + (size_t)n * 64);
    const float4* wp4 = (const float4*)(W + ((size_t)sm * 64 + o) * 64);
    float acc = b[sm * 64 + o];
    #pragma unroll 4
    for (int d4 = 0; d4 < 16; ++d4) {
        float4 xv = xp4[d4], wv = wp4[d4];
        acc = fmaf(xv.x, wv.x, fmaf(xv.y, wv.y, fmaf(xv.z, wv.z, fmaf(xv.w, wv.w, acc))));
    }
    qkv[(size_t)sm * N * 64 + (size_t)(o >> 3) * N * 8 + (size_t)n * 8 + (o & 7)] = acc;
}

// ---------------- MHSA flash attention, hd=8, fp16 QK via v_dot2 ----------------
// Lane = j; wave owns 8 q-rows. Q,K packed fp16 (halves regs + score ops);
// V,acc stay f32. LDS tile [64 j][4 float4-slots]: slot0 = K(8 fp16),
// slot1/2 = V f32, slot-swizzled. No-max exp2 softmax (qs folds 1/sqrt(8)*log2e).
#define QLOADH(qa, qb, qc, qd, r) { int row_ = row0 + (r); if (row_ >= N) row_ = 0; \
    const float4* qp_ = (const float4*)(qsl + (size_t)row_ * 8);                  \
    float4 a_ = qp_[0], b_ = qp_[1];                                              \
    qa = h2{(_Float16)(a_.x * qs), (_Float16)(a_.y * qs)};                        \
    qb = h2{(_Float16)(a_.z * qs), (_Float16)(a_.w * qs)};                        \
    qc = h2{(_Float16)(b_.x * qs), (_Float16)(b_.y * qs)};                        \
    qd = h2{(_Float16)(b_.z * qs), (_Float16)(b_.w * qs)}; }

#define ROWSTEPH(qa, qb, qc, qd, ca, cb, lr) {                                    \
    float s_ = __builtin_amdgcn_fdot2(qa, kk0,                                    \
               __builtin_amdgcn_fdot2(qb, kk1,                                    \
               __builtin_amdgcn_fdot2(qc, kk2,                                    \
               __builtin_amdgcn_fdot2(qd, kk3, 0.f, false), false), false), false);\
    float p_ = exp2f(s_); lr += p_;                                               \
    ca.x = fmaf(p_, vv0.x, ca.x); ca.y = fmaf(p_, vv0.y, ca.y);                   \
    ca.z = fmaf(p_, vv0.z, ca.z); ca.w = fmaf(p_, vv0.w, ca.w);                   \
    cb.x = fmaf(p_, vv1.x, cb.x); cb.y = fmaf(p_, vv1.y, cb.y);                   \
    cb.z = fmaf(p_, vv1.z, cb.z); cb.w = fmaf(p_, vv1.w, cb.w); }

#define BF3A(v) { v += __shfl_xor(v, 1, 64); v += __shfl_xor(v, 2, 64);           \
                  v += __shfl_xor(v, 4, 64); }

#define ROWOUT(ca, cb, lr, r) {                                                   \
    BF3A(ca.x); BF3A(ca.y); BF3A(ca.z); BF3A(ca.w);                               \
    BF3A(cb.x); BF3A(cb.y); BF3A(cb.z); BF3A(cb.w); BF3A(lr);                     \
    int sel_ = ln & 7;                                                            \
    float t_ = (sel_ == 0) ? ca.x : (sel_ == 1) ? ca.y : (sel_ == 2) ? ca.z :     \
               (sel_ == 3) ? ca.w : (sel_ == 4) ? cb.x : (sel_ == 5) ? cb.y :     \
               (sel_ == 6) ? cb.z : cb.w;                                         \
    t_ += __shfl_xor(t_, 8, 64); t_ += __shfl_xor(t_, 16, 64);                    \
    t_ += __shfl_xor(t_, 32, 64);                                                 \
    lr += __shfl_xor(lr, 8, 64); lr += __shfl_xor(lr, 16, 64);                    \
    lr += __shfl_xor(lr, 32, 64);                                                 \
    int row_ = row0 + (r);                                                        \
    if (ln < 8 && row_ < N)                                                       \
        atomicAdd(&accum[(size_t)row_ * 64 + hh * 8 + ln], t_ / (lr - phantom)); }

__global__ __launch_bounds__(256, 4)
void k_attn(const float* __restrict__ qkv, float* __restrict__ accum, int N) {
    __shared__ float4 kvt[256];            // [64 j][4 slots], slot-swizzled
    int bid = blockIdx.x;
    int m  = bid & 7;                      // same m -> same XCD (L2 locality)
    int hh = (bid >> 3) & 7;
    int rt = bid >> 6;
    int wid = threadIdx.x >> 6, ln = threadIdx.x & 63;
    int row0 = rt * 32 + wid * 8;
    const float* qsl = qkv + (size_t)m        * N * 64 + (size_t)hh * N * 8;
    const float* ksl = qkv + (size_t)(8 + m)  * N * 64 + (size_t)hh * N * 8;
    const float* vsl = qkv + (size_t)(16 + m) * N * 64 + (size_t)hh * N * 8;

    const float qs = 0.35355339059327373f * 1.44269504088896341f;  // 1/sqrt(8)*log2(e)
    h2 q0a, q0b, q0c, q0d, q1a, q1b, q1c, q1d, q2a, q2b, q2c, q2d, q3a, q3b, q3c, q3d;
    h2 q4a, q4b, q4c, q4d, q5a, q5b, q5c, q5d, q6a, q6b, q6c, q6d, q7a, q7b, q7c, q7d;
    QLOADH(q0a, q0b, q0c, q0d, 0) QLOADH(q1a, q1b, q1c, q1d, 1)
    QLOADH(q2a, q2b, q2c, q2d, 2) QLOADH(q3a, q3b, q3c, q3d, 3)
    QLOADH(q4a, q4b, q4c, q4d, 4) QLOADH(q5a, q5b, q5c, q5d, 5)
    QLOADH(q6a, q6b, q6c, q6d, 6) QLOADH(q7a, q7b, q7c, q7d, 7)

    // staging roles per j (4 threads): part0 = K lo (cvt fp16), part3 = K hi,
    // part1 = V lo (f32), part2 = V hi
    int sj = threadIdx.x >> 2;
    int part = threadIdx.x & 3;
    bool isK = (part == 0) | (part == 3);
    const float* sb = isK ? ksl : vsl;
    int halfo = (part & 2) ? 4 : 0;        // part2/part3 take floats 4-7
    int slot_base = isK ? 0 : (part == 1 ? 1 : 2);
    int slot = slot_base ^ ((sj >> 1) & 3);
    float4* vdst = &kvt[sj * 4 + slot];
    float2* kdst = (float2*)((char*)&kvt[sj * 4 + slot] + ((part == 3) ? 8 : 0));

    int Tt = (N + 63) >> 6;
    float4 pre = (sj < N) ? *(const float4*)(sb + (size_t)sj * 8 + halfo)
                          : make_float4(0.f, 0.f, 0.f, 0.f);

    float l0 = 0.f, l1 = 0.f, l2 = 0.f, l3 = 0.f, l4 = 0.f, l5 = 0.f, l6 = 0.f, l7 = 0.f;
    float4 z4 = make_float4(0.f, 0.f, 0.f, 0.f);
    float4 c0a = z4, c0b = z4, c1a = z4, c1b = z4, c2a = z4, c2b = z4, c3a = z4, c3b = z4;
    float4 c4a = z4, c4b = z4, c5a = z4, c5b = z4, c6a = z4, c6b = z4, c7a = z4, c7b = z4;

    int sw = (ln >> 1) & 3;
    const float4* rbase = &kvt[ln * 4];

    for (int t = 0; t < Tt; ++t) {
        __syncthreads();                   // previous tile fully consumed
        if (isK) {
            h2 lo = h2{(_Float16)pre.x, (_Float16)pre.y};
            h2 hi = h2{(_Float16)pre.z, (_Float16)pre.w};
            float2 st;
            st.x = __builtin_bit_cast(float, lo);
            st.y = __builtin_bit_cast(float, hi);
            *kdst = st;
        } else {
            *vdst = pre;
        }
        __syncthreads();                   // tile ready
        if (t + 1 < Tt) {
            int j = (t + 1) * 64 + sj;
            pre = (j < N) ? *(const float4*)(sb + (size_t)j * 8 + halfo)
                          : make_float4(0.f, 0.f, 0.f, 0.f);
        }
        float4 kf = rbase[0 ^ sw];
        h2 kk0 = __builtin_bit_cast(h2, kf.x);
        h2 kk1 = __builtin_bit_cast(h2, kf.y);
        h2 kk2 = __builtin_bit_cast(h2, kf.z);
        h2 kk3 = __builtin_bit_cast(h2, kf.w);
        float4 vv0 = rbase[1 ^ sw], vv1 = rbase[2 ^ sw];
        ROWSTEPH(q0a, q0b, q0c, q0d, c0a, c0b, l0)
        ROWSTEPH(q1a, q1b, q1c, q1d, c1a, c1b, l1)
        ROWSTEPH(q2a, q2b, q2c, q2d, c2a, c2b, l2)
        ROWSTEPH(q3a, q3b, q3c, q3d, c3a, c3b, l3)
        ROWSTEPH(q4a, q4b, q4c, q4d, c4a, c4b, l4)
        ROWSTEPH(q5a, q5b, q5c, q5d, c5a, c5b, l5)
        ROWSTEPH(q6a, q6b, q6c, q6d, c6a, c6b, l6)
        ROWSTEPH(q7a, q7b, q7c, q7d, c7a, c7b, l7)
    }

    float phantom = (float)(Tt * 64 - N);  // zero-staged tails contribute exp2(0)=1
    ROWOUT(c0a, c0b, l0, 0) ROWOUT(c1a, c1b, l1, 1)
    ROWOUT(c2a, c2b, l2, 2) ROWOUT(c3a, c3b, l3, 3)
    ROWOUT(c4a, c4b, l4, 4) ROWOUT(c5a, c5b, l5, 5)
    ROWOUT(c6a, c6b, l6, 6) ROWOUT(c7a, c7b, l7, 7)
}

// out = LN(acc + resid) * g + b ; one wave (64 lanes) per row
__global__ void k_ln(const float* __restrict__ acc, const float* __restrict__ resid,
                     const float* __restrict__ g, const float* __restrict__ b,
                     float* __restrict__ out, int N) {
    int r = blockIdx.x * 4 + (threadIdx.x >> 6);
    int d = threadIdx.x & 63;
    if (r >= N) return;
    float v = acc[(size_t)r * 64 + d] + resid[(size_t)r * 64 + d];
    float s = v;
    for (int off = 32; off; off >>= 1) s += __shfl_xor(s, off, 64);
    float mean = s * (1.f / 64.f);
    float c = v - mean;
    float vv = c * c;
    for (int off = 32; off; off >>= 1) vv += __shfl_xor(vv, off, 64);
    float var = vv * (1.f / 64.f);
    out[(size_t)r * 64 + d] = c * rsqrtf(var + 1e-5f) * g[d] + b[d];
}

// ---------------- Final MLP: LDS-tiled 3-layer GEMM ----------------
#define MLP_STEP(ai, xi) {                                                        \
    ai.x = fmaf(xi.x, w0.x, fmaf(xi.y, w0.y, fmaf(xi.z, w0.z, fmaf(xi.w, w0.w, ai.x)))); \
    ai.y = fmaf(xi.x, w1.x, fmaf(xi.y, w1.y, fmaf(xi.z, w1.z, fmaf(xi.w, w1.w, ai.y)))); \
    ai.z = fmaf(xi.x, w2.x, fmaf(xi.y, w2.y, fmaf(xi.z, w2.z, fmaf(xi.w, w2.w, ai.z)))); \
    ai.w = fmaf(xi.x, w3.x, fmaf(xi.y, w3.y, fmaf(xi.z, w3.z, fmaf(xi.w, w3.w, ai.w)))); }

#define MLP_LAYER(B_)                                                             \
    a0 = z4; a1 = z4; a2 = z4; a3 = z4; a4 = z4; a5 = z4; a6 = z4; a7 = z4;       \
    _Pragma("unroll 4")                                                           \
    for (int k4 = 0; k4 < 32; ++k4) {                                             \
        float4 w0 = sW4[og][k4 ^ swz];                                            \
        float4 w1 = sW4[og + 32][k4 ^ swz];                                       \
        float4 w2 = sW4[og + 64][k4 ^ swz];                                       \
        float4 w3 = sW4[og + 96][k4 ^ swz];                                       \
        float4 x0 = sX4[pb + 0][k4], x1 = sX4[pb + 1][k4];                        \
        float4 x2 = sX4[pb + 2][k4], x3 = sX4[pb + 3][k4];                        \
        float4 x4 = sX4[pb + 4][k4], x5 = sX4[pb + 5][k4];                        \
        float4 x6 = sX4[pb + 6][k4], x7 = sX4[pb + 7][k4];                        \
        MLP_STEP(a0, x0) MLP_STEP(a1, x1) MLP_STEP(a2, x2) MLP_STEP(a3, x3)       \
        MLP_STEP(a4, x4) MLP_STEP(a5, x5) MLP_STEP(a6, x6) MLP_STEP(a7, x7)       \
    }                                                                             \
    {                                                                             \
        float bo0 = B_[og], bo1 = B_[og + 32], bo2 = B_[og + 64], bo3 = B_[og + 96]; \
        a0.x += bo0; a0.y += bo1; a0.z += bo2; a0.w += bo3;                       \
        a1.x += bo0; a1.y += bo1; a1.z += bo2; a1.w += bo3;                       \
        a2.x += bo0; a2.y += bo1; a2.z += bo2; a2.w += bo3;                       \
        a3.x += bo0; a3.y += bo1; a3.z += bo2; a3.w += bo3;                       \
        a4.x += bo0; a4.y += bo1; a4.z += bo2; a4.w += bo3;                       \
        a5.x += bo0; a5.y += bo1; a5.z += bo2; a5.w += bo3;                       \
        a6.x += bo0; a6.y += bo1; a6.z += bo2; a6.w += bo3;                       \
        a7.x += bo0; a7.y += bo1; a7.z += bo2; a7.w += bo3;                       \
    }

#define MLP_HWRITE(ai, i) {                                                       \
    float* hp_ = sXf + (size_t)(pb + (i)) * 128;                                  \
    hp_[og]      = ai.x > 0.f ? ai.x : 0.f;                                       \
    hp_[og + 32] = ai.y > 0.f ? ai.y : 0.f;                                       \
    hp_[og + 64] = ai.z > 0.f ? ai.z : 0.f;                                       \
    hp_[og + 96] = ai.w > 0.f ? ai.w : 0.f; }

#define MLP_WLOAD(Wg_) {                                                          \
    const float4* wsrc_ = (const float4*)(Wg_);                                   \
    _Pragma("unroll")                                                             \
    for (int u = 0; u < 16; ++u) {                                                \
        int f4 = u * 256 + t;                                                     \
        int o_ = f4 >> 5, k4_ = f4 & 31;                                          \
        sW4[o_][k4_ ^ (o_ & 7)] = wsrc_[f4];                                      \
    } }

__global__ __launch_bounds__(256, 1)
void k_mlp(const float* __restrict__ px, const float* __restrict__ dx,
           const int* __restrict__ pairs,
           const float* __restrict__ W1, const float* __restrict__ b1,
           const float* __restrict__ W2, const float* __restrict__ b2,
           const float* __restrict__ W3, const float* __restrict__ b3,
           float* __restrict__ out) {
    __shared__ float4 sX4[64][32];         // 32 KB: x tile, then h1, then h2
    __shared__ float4 sW4[128][32];        // 64 KB: W1, then W2 (swizzled)
    float* sXf = (float*)sX4;
    int t = threadIdx.x;
    int base = blockIdx.x * 64;

    // gather X = concat(px[ip], dx[id]) for 64 pairs
    #pragma unroll
    for (int u = 0; u < 8; ++u) {
        int idx = u * 256 + t;
        int p = idx >> 5, c4 = idx & 31;
        int ip = pairs[(base + p) * 2], id = pairs[(base + p) * 2 + 1];
        float4 v = (c4 < 16) ? ((const float4*)px)[(size_t)ip * 16 + c4]
                             : ((const float4*)dx)[(size_t)id * 16 + (c4 - 16)];
        sX4[p][c4] = v;
    }
    MLP_WLOAD(W1)
    __syncthreads();

    int og = t & 31;                       // out group: o = og + 32j
    int pb = (t >> 5) * 8;                 // first of 8 pairs
    int swz = og & 7;                      // W k4-swizzle (32j keeps o&7 = og&7)
    float4 z4 = make_float4(0.f, 0.f, 0.f, 0.f);
    float4 a0, a1, a2, a3, a4, a5, a6, a7;

    MLP_LAYER(b1)                          // fc1 from X
    __syncthreads();                       // all fc1 reads done
    MLP_HWRITE(a0, 0) MLP_HWRITE(a1, 1) MLP_HWRITE(a2, 2) MLP_HWRITE(a3, 3)
    MLP_HWRITE(a4, 4) MLP_HWRITE(a5, 5) MLP_HWRITE(a6, 6) MLP_HWRITE(a7, 7)
    MLP_WLOAD(W2)
    __syncthreads();                       // h1 + W2 ready

    MLP_LAYER(b2)                          // fc2 from h1
    __syncthreads();                       // all fc2 reads done
    MLP_HWRITE(a0, 0) MLP_HWRITE(a1, 1) MLP_HWRITE(a2, 2) MLP_HWRITE(a3, 3)
    MLP_HWRITE(a4, 4) MLP_HWRITE(a5, 5) MLP_HWRITE(a6, 6) MLP_HWRITE(a7, 7)
    __syncthreads();                       // h2 ready

    // fc3: out[p] = b3 + h2[p] . W3   (4 threads per pair, shfl-reduce)
    {
        int p = t >> 2, qd = t & 3;
        const float4* w3 = (const float4*)W3;
        float sum = 0.f;
        #pragma unroll
        for (int u = 0; u < 8; ++u) {
            float4 h = sX4[p][qd * 8 + u];
            float4 w = w3[qd * 8 + u];
            sum += h.x * w.x + h.y * w.y + h.z * w.z + h.w * w.w;
        }
        sum += __shfl_xor(sum, 1, 64);
        sum += __shfl_xor(sum, 2, 64);
        if ((t & 3) == 0) out[base + p] = sum + b3[0];
    }
}

extern "C" void kernel_launch(void* const* d_in, const int* in_sizes, int n_in,
                              void* d_out, int out_size, void* d_ws, size_t ws_size,
                              hipStream_t stream) {
    const float* pfeat = (const float*)d_in[0];
    const float* padj  = (const float*)d_in[1];
    const float* dfeat = (const float*)d_in[2];
    const float* dadj  = (const float*)d_in[3];
    const int*   pairs = (const int*)d_in[4];
    const float* fc1W = (const float*)d_in[33];
    const float* fc1b = (const float*)d_in[34];
    const float* fc2W = (const float*)d_in[35];
    const float* fc2b = (const float*)d_in[36];
    const float* fc3W = (const float*)d_in[37];
    const float* fc3b = (const float*)d_in[38];

    float* ws = (float*)d_ws;
    float* buf_Wh   = ws;                              // 8*2048*8   = 131072
    float* buf_s1   = buf_Wh   + 8 * 2048 * 8;         // 16384
    float* buf_s2   = buf_s1   + 8 * 2048;             // 16384
    float* buf_gat  = buf_s2   + 8 * 2048;             // 131072
    float* buf_proj = buf_gat  + 2048 * 64;            // 131072
    float* buf_qkv  = buf_proj + 2048 * 64;            // 3145728
    float* buf_acc  = buf_qkv  + 24 * 2048 * 64;       // 131072
    float* buf_x    = buf_acc  + 2048 * 64;            // 131072
    float* buf_px   = buf_x    + 2048 * 64;            // 131072
    float* buf_dx   = buf_px   + 2048 * 64;            // 96000

    auto run_branch = [&](const float* feat, const float* adj, int N, int F,
                          void* const* w, float* xout) {
        const float* g1W = (const float*)w[0];
        const float* g1a = (const float*)w[1];
        const float* p1W = (const float*)w[2];
        const float* s1W = (const float*)w[3];
        const float* s1b = (const float*)w[4];
        const float* l1g = (const float*)w[5];
        const float* l1b = (const float*)w[6];
        const float* g2W = (const float*)w[7];
        const float* g2a = (const float*)w[8];
        const float* p2W = (const float*)w[9];
        const float* s2W = (const float*)w[10];
        const float* s2b = (const float*)w[11];
        const float* l2g = (const float*)w[12];
        const float* l2b = (const float*)w[13];

        int attnGrid = 64 * ((N + 31) / 32);   // bid: m=bid&7, h=(bid>>3)&7, rt=bid>>6

        // ---- layer 1 ----
        k_gat_wh<<<(64 * N + 255) / 256, 256, 0, stream>>>(feat, g1W, buf_Wh, N, F);
        k_gat_s<<<(8 * N + 255) / 256, 256, 0, stream>>>(buf_Wh, g1a, buf_s1, buf_s2, N);
        k_gat_attn<<<N, 256, 0, stream>>>(adj, buf_s1, buf_s2, buf_Wh, buf_gat, N);
        k_proj<<<(64 * N + 255) / 256, 256, 0, stream>>>(buf_gat, p1W, buf_proj, N);
        k_qkv<<<(1536 * N + 255) / 256, 256, 0, stream>>>(buf_proj, s1W, s1b, buf_qkv, N);
        hipMemsetAsync(buf_acc, 0, (size_t)N * 64 * sizeof(float), stream);
        k_attn<<<attnGrid, 256, 0, stream>>>(buf_qkv, buf_acc, N);
        k_ln<<<(N + 3) / 4, 256, 0, stream>>>(buf_acc, buf_proj, l1g, l1b, buf_x, N);
        // ---- layer 2 ----
        k_gat_wh<<<(64 * N + 255) / 256, 256, 0, stream>>>(buf_x, g2W, buf_Wh, N, EMB);
        k_gat_s<<<(8 * N + 255) / 256, 256, 0, stream>>>(buf_Wh, g2a, buf_s1, buf_s2, N);
        k_gat_attn<<<N, 256, 0, stream>>>(adj, buf_s1, buf_s2, buf_Wh, buf_gat, N);
        k_proj<<<(64 * N + 255) / 256, 256, 0, stream>>>(buf_gat, p2W, buf_proj, N);
        k_qkv<<<(1536 * N + 255) / 256, 256, 0, stream>>>(buf_proj, s2W, s2b, buf_qkv, N);
        hipMemsetAsync(buf_acc, 0, (size_t)N * 64 * sizeof(float), stream);
        k_attn<<<attnGrid, 256, 0, stream>>>(buf_qkv, buf_acc, N);
        k_ln<<<(N + 3) / 4, 256, 0, stream>>>(buf_acc, buf_proj, l2g, l2b, xout, N);
    };

    run_branch(pfeat, padj, NPROT, 512, d_in + 5, buf_px);
    run_branch(dfeat, dadj, NDRUG, 256, d_in + 19, buf_dx);

    k_mlp<<<NPAIR / 64, 256, 0, stream>>>(buf_px, buf_dx, pairs,
                                          fc1W, fc1b, fc2W, fc2b, fc3W, fc3b,
                                          (float*)d_out);
}

// Round 15
// 1198.838 us; speedup vs baseline: 4.9690x; 1.2817x over previous
//
#include <hip/hip_runtime.h>
#include <math.h>

#define NHID 8
#define NHEADS 8
#define EMB 64
#define NPROT 2048
#define NDRUG 1500
#define NPAIR 16384

typedef _Float16 h2 __attribute__((ext_vector_type(2)));
typedef float f4 __attribute__((ext_vector_type(4)));

// ---------------- GAT: Wh[h][n][o] = sum_f h[n,f] * W[h,f,o] ----------------
__global__ void k_gat_wh(const float* __restrict__ h, const float* __restrict__ W,
                         float* __restrict__ Wh, int N, int F) {
    int idx = blockIdx.x * 256 + threadIdx.x;       // flat (hh, n, o)
    int total = NHEADS * N * NHID;
    if (idx >= total) return;
    int o  = idx & 7;
    int n  = (idx >> 3) % N;
    int hh = idx / (N * 8);
    const float4* hp4 = (const float4*)(h + (size_t)n * F);
    const float* wp = W + (size_t)hh * F * 8 + o;
    float acc = 0.f;
    for (int f4i = 0; f4i < (F >> 2); ++f4i) {
        float4 hv = hp4[f4i];
        int fb = f4i * 32;                           // (f4*4)*8
        acc = fmaf(hv.x, wp[fb], fmaf(hv.y, wp[fb + 8],
              fmaf(hv.z, wp[fb + 16], fmaf(hv.w, wp[fb + 24], acc))));
    }
    Wh[idx] = acc;
}

// s1[h][n] = Wh[h][n][:] . a[h][:8];  s2 uses a[h][8:16]
__global__ void k_gat_s(const float* __restrict__ Wh, const float* __restrict__ a,
                        float* __restrict__ s1, float* __restrict__ s2, int N) {
    int idx = blockIdx.x * 256 + threadIdx.x;       // h*N + n
    if (idx >= NHEADS * N) return;
    int hh = idx / N;
    const float* wp = Wh + (size_t)idx * 8;
    const float* ap = a + hh * 16;
    float x1 = 0.f, x2 = 0.f;
    for (int o = 0; o < 8; ++o) { x1 += wp[o] * ap[o]; x2 += wp[o] * ap[8 + o]; }
    s1[idx] = x1; s2[idx] = x2;
}

// One block per row i. 8 concurrent head-groups of 32 lanes each.
__global__ void k_gat_attn(const float* __restrict__ adj, const float* __restrict__ s1,
                           const float* __restrict__ s2, const float* __restrict__ Wh,
                           float* __restrict__ out, int N) {
    __shared__ int nbr[2048];
    __shared__ int s_cnt;
    int i = blockIdx.x;
    int tid = threadIdx.x;
    if (tid == 0) s_cnt = 0;
    __syncthreads();
    const float* arow = adj + (size_t)i * N;
    for (int j = tid; j < N; j += 256)
        if (arow[j] > 0.f) { int p = atomicAdd(&s_cnt, 1); nbr[p] = j; }
    __syncthreads();
    int cnt = s_cnt;
    int g  = tid >> 5;          // head index 0..7
    int ln = tid & 31;          // lane within head-group
    float si = s1[g * N + i];
    const float* s2h = s2 + g * N;
    // pass 1: group max of leakyrelu(si + s2[j])
    float mx = -1e30f;
    for (int t = ln; t < cnt; t += 32) {
        float e = si + s2h[nbr[t]];
        e = e > 0.f ? e : 0.2f * e;
        mx = fmaxf(mx, e);
    }
    #pragma unroll
    for (int off = 16; off; off >>= 1) mx = fmaxf(mx, __shfl_xor(mx, off, 32));
    // pass 2: exp-sum + weighted accumulation of Wh rows
    float acc[8] = {0, 0, 0, 0, 0, 0, 0, 0};
    float lsum = 0.f;
    for (int t = ln; t < cnt; t += 32) {
        int j = nbr[t];
        float e = si + s2h[j];
        e = e > 0.f ? e : 0.2f * e;
        float p = __expf(e - mx);
        lsum += p;
        const float4* wp = (const float4*)(Wh + ((size_t)g * N + j) * 8);
        float4 w0 = wp[0], w1 = wp[1];
        acc[0] += p * w0.x; acc[1] += p * w0.y; acc[2] += p * w0.z; acc[3] += p * w0.w;
        acc[4] += p * w1.x; acc[5] += p * w1.y; acc[6] += p * w1.z; acc[7] += p * w1.w;
    }
    #pragma unroll
    for (int off = 16; off; off >>= 1) {
        lsum += __shfl_xor(lsum, off, 32);
        #pragma unroll
        for (int d = 0; d < 8; ++d) acc[d] += __shfl_xor(acc[d], off, 32);
    }
    if (ln == 0) {
        float inv = 1.f / lsum;
        #pragma unroll
        for (int d = 0; d < 8; ++d) {
            float r = acc[d] * inv;
            out[(size_t)i * 64 + g * 8 + d] = r > 0.f ? r : 0.f;   // relu
        }
    }
}

// out[n][o] = sum_d in[n][d] * W[o][d]   (x @ W.T, no bias)
__global__ void k_proj(const float* __restrict__ in, const float* __restrict__ W,
                       float* __restrict__ out, int N) {
    int idx = blockIdx.x * 256 + threadIdx.x;
    if (idx >= N * 64) return;
    int o = idx & 63, n = idx >> 6;
    const float* ip = in + (size_t)n * 64;
    const float* wp = W + (size_t)o * 64;
    float acc = 0.f;
    for (int d = 0; d < 64; ++d) acc += ip[d] * wp[d];
    out[idx] = acc;
}

// qkv layout: [sm][h][n][8]  (slice per (module,head) contiguous)
__global__ void k_qkv(const float* __restrict__ x, const float* __restrict__ W,
                      const float* __restrict__ b, float* __restrict__ qkv, int N) {
    int idx = blockIdx.x * 256 + threadIdx.x;
    int total = 24 * N * 64;
    if (idx >= total) return;
    int o = idx & 63;
    int n = (idx >> 6) % N;
    int sm = idx / (N * 64);
    const float4* xp4 = (const float4*)(x + (size_t)n * 64);
    const float4* wp4 = (const float4*)(W + ((size_t)sm * 64 + o) * 64);
    float acc = b[sm * 64 + o];
    #pragma unroll 4
    for (int d4 = 0; d4 < 16; ++d4) {
        float4 xv = xp4[d4], wv = wp4[d4];
        acc = fmaf(xv.x, wv.x, fmaf(xv.y, wv.y, fmaf(xv.z, wv.z, fmaf(xv.w, wv.w, acc))));
    }
    qkv[(size_t)sm * N * 64 + (size_t)(o >> 3) * N * 8 + (size_t)n * 8 + (o & 7)] = acc;
}

// ---------------- MHSA flash attention, hd=8, fp16 QK via v_dot2 ----------------
// Lane = j; wave owns 8 q-rows. Q,K packed fp16; V,acc f32 in ext-vector float4
// with __builtin_elementwise_fma -> v_pk_fma_f32 (packed PV, halves FMA count).
// exp2 via __builtin_amdgcn_exp2f (bare v_exp_f32, no ocml fixup).
#define QLOADH(qa, qb, qc, qd, r) { int row_ = row0 + (r); if (row_ >= N) row_ = 0; \
    const f4* qp_ = (const f4*)(qsl + (size_t)row_ * 8);                          \
    f4 a_ = qp_[0], b_ = qp_[1];                                                  \
    qa = h2{(_Float16)(a_.x * qs), (_Float16)(a_.y * qs)};                        \
    qb = h2{(_Float16)(a_.z * qs), (_Float16)(a_.w * qs)};                        \
    qc = h2{(_Float16)(b_.x * qs), (_Float16)(b_.y * qs)};                        \
    qd = h2{(_Float16)(b_.z * qs), (_Float16)(b_.w * qs)}; }

#define ROWSTEPH(qa, qb, qc, qd, ca, cb, lr) {                                    \
    float s_ = __builtin_amdgcn_fdot2(qa, kk0,                                    \
               __builtin_amdgcn_fdot2(qb, kk1,                                    \
               __builtin_amdgcn_fdot2(qc, kk2,                                    \
               __builtin_amdgcn_fdot2(qd, kk3, 0.f, false), false), false), false);\
    float p_ = __builtin_amdgcn_exp2f(s_); lr += p_;                              \
    f4 pv_ = {p_, p_, p_, p_};                                                    \
    ca = __builtin_elementwise_fma(pv_, vv0, ca);                                 \
    cb = __builtin_elementwise_fma(pv_, vv1, cb); }

#define BF3A(v) { v += __shfl_xor(v, 1, 64); v += __shfl_xor(v, 2, 64);           \
                  v += __shfl_xor(v, 4, 64); }

#define ROWOUT(ca, cb, lr, r) {                                                   \
    float ax_ = ca.x, ay_ = ca.y, az_ = ca.z, aw_ = ca.w;                         \
    float bx_ = cb.x, by_ = cb.y, bz_ = cb.z, bw_ = cb.w;                         \
    BF3A(ax_); BF3A(ay_); BF3A(az_); BF3A(aw_);                                   \
    BF3A(bx_); BF3A(by_); BF3A(bz_); BF3A(bw_); BF3A(lr);                         \
    int sel_ = ln & 7;                                                            \
    float t_ = (sel_ == 0) ? ax_ : (sel_ == 1) ? ay_ : (sel_ == 2) ? az_ :        \
               (sel_ == 3) ? aw_ : (sel_ == 4) ? bx_ : (sel_ == 5) ? by_ :        \
               (sel_ == 6) ? bz_ : bw_;                                           \
    t_ += __shfl_xor(t_, 8, 64); t_ += __shfl_xor(t_, 16, 64);                    \
    t_ += __shfl_xor(t_, 32, 64);                                                 \
    lr += __shfl_xor(lr, 8, 64); lr += __shfl_xor(lr, 16, 64);                    \
    lr += __shfl_xor(lr, 32, 64);                                                 \
    int row_ = row0 + (r);                                                        \
    if (ln < 8 && row_ < N)                                                       \
        atomicAdd(&accum[(size_t)row_ * 64 + hh * 8 + ln], t_ / (lr - phantom)); }

__global__ __launch_bounds__(256, 3)
void k_attn(const float* __restrict__ qkv, float* __restrict__ accum, int N) {
    __shared__ f4 kvt[256];                // [64 j][4 slots], slot-swizzled
    int bid = blockIdx.x;
    int m  = bid & 7;                      // same m -> same XCD (L2 locality)
    int hh = (bid >> 3) & 7;
    int rt = bid >> 6;
    int wid = threadIdx.x >> 6, ln = threadIdx.x & 63;
    int row0 = rt * 32 + wid * 8;
    const float* qsl = qkv + (size_t)m        * N * 64 + (size_t)hh * N * 8;
    const float* ksl = qkv + (size_t)(8 + m)  * N * 64 + (size_t)hh * N * 8;
    const float* vsl = qkv + (size_t)(16 + m) * N * 64 + (size_t)hh * N * 8;

    const float qs = 0.35355339059327373f * 1.44269504088896341f;  // 1/sqrt(8)*log2(e)
    h2 q0a, q0b, q0c, q0d, q1a, q1b, q1c, q1d, q2a, q2b, q2c, q2d, q3a, q3b, q3c, q3d;
    h2 q4a, q4b, q4c, q4d, q5a, q5b, q5c, q5d, q6a, q6b, q6c, q6d, q7a, q7b, q7c, q7d;
    QLOADH(q0a, q0b, q0c, q0d, 0) QLOADH(q1a, q1b, q1c, q1d, 1)
    QLOADH(q2a, q2b, q2c, q2d, 2) QLOADH(q3a, q3b, q3c, q3d, 3)
    QLOADH(q4a, q4b, q4c, q4d, 4) QLOADH(q5a, q5b, q5c, q5d, 5)
    QLOADH(q6a, q6b, q6c, q6d, 6) QLOADH(q7a, q7b, q7c, q7d, 7)

    // staging roles per j (4 threads): part0 = K lo (cvt fp16), part3 = K hi,
    // part1 = V lo (f32), part2 = V hi
    int sj = threadIdx.x >> 2;
    int part = threadIdx.x & 3;
    bool isK = (part == 0) | (part == 3);
    const float* sb = isK ? ksl : vsl;
    int halfo = (part & 2) ? 4 : 0;        // part2/part3 take floats 4-7
    int slot_base = isK ? 0 : (part == 1 ? 1 : 2);
    int slot = slot_base ^ ((sj >> 1) & 3);
    f4* vdst = &kvt[sj * 4 + slot];
    float2* kdst = (float2*)((char*)&kvt[sj * 4 + slot] + ((part == 3) ? 8 : 0));

    f4 zf4 = {0.f, 0.f, 0.f, 0.f};
    int Tt = (N + 63) >> 6;
    f4 pre = (sj < N) ? *(const f4*)(sb + (size_t)sj * 8 + halfo) : zf4;

    float l0 = 0.f, l1 = 0.f, l2 = 0.f, l3 = 0.f, l4 = 0.f, l5 = 0.f, l6 = 0.f, l7 = 0.f;
    f4 c0a = zf4, c0b = zf4, c1a = zf4, c1b = zf4, c2a = zf4, c2b = zf4, c3a = zf4, c3b = zf4;
    f4 c4a = zf4, c4b = zf4, c5a = zf4, c5b = zf4, c6a = zf4, c6b = zf4, c7a = zf4, c7b = zf4;

    int sw = (ln >> 1) & 3;
    const f4* rbase = &kvt[ln * 4];

    for (int t = 0; t < Tt; ++t) {
        __syncthreads();                   // previous tile fully consumed
        if (isK) {
            h2 lo = h2{(_Float16)pre.x, (_Float16)pre.y};
            h2 hi = h2{(_Float16)pre.z, (_Float16)pre.w};
            float2 st;
            st.x = __builtin_bit_cast(float, lo);
            st.y = __builtin_bit_cast(float, hi);
            *kdst = st;
        } else {
            *vdst = pre;
        }
        __syncthreads();                   // tile ready
        if (t + 1 < Tt) {
            int j = (t + 1) * 64 + sj;
            pre = (j < N) ? *(const f4*)(sb + (size_t)j * 8 + halfo) : zf4;
        }
        f4 kf = rbase[0 ^ sw];
        h2 kk0 = __builtin_bit_cast(h2, kf.x);
        h2 kk1 = __builtin_bit_cast(h2, kf.y);
        h2 kk2 = __builtin_bit_cast(h2, kf.z);
        h2 kk3 = __builtin_bit_cast(h2, kf.w);
        f4 vv0 = rbase[1 ^ sw], vv1 = rbase[2 ^ sw];
        ROWSTEPH(q0a, q0b, q0c, q0d, c0a, c0b, l0)
        ROWSTEPH(q1a, q1b, q1c, q1d, c1a, c1b, l1)
        ROWSTEPH(q2a, q2b, q2c, q2d, c2a, c2b, l2)
        ROWSTEPH(q3a, q3b, q3c, q3d, c3a, c3b, l3)
        ROWSTEPH(q4a, q4b, q4c, q4d, c4a, c4b, l4)
        ROWSTEPH(q5a, q5b, q5c, q5d, c5a, c5b, l5)
        ROWSTEPH(q6a, q6b, q6c, q6d, c6a, c6b, l6)
        ROWSTEPH(q7a, q7b, q7c, q7d, c7a, c7b, l7)
    }

    float phantom = (float)(Tt * 64 - N);  // zero-staged tails contribute exp2(0)=1
    ROWOUT(c0a, c0b, l0, 0) ROWOUT(c1a, c1b, l1, 1)
    ROWOUT(c2a, c2b, l2, 2) ROWOUT(c3a, c3b, l3, 3)
    ROWOUT(c4a, c4b, l4, 4) ROWOUT(c5a, c5b, l5, 5)
    ROWOUT(c6a, c6b, l6, 6) ROWOUT(c7a, c7b, l7, 7)
}

// out = LN(acc + resid) * g + b ; one wave (64 lanes) per row
__global__ void k_ln(const float* __restrict__ acc, const float* __restrict__ resid,
                     const float* __restrict__ g, const float* __restrict__ b,
                     float* __restrict__ out, int N) {
    int r = blockIdx.x * 4 + (threadIdx.x >> 6);
    int d = threadIdx.x & 63;
    if (r >= N) return;
    float v = acc[(size_t)r * 64 + d] + resid[(size_t)r * 64 + d];
    float s = v;
    for (int off = 32; off; off >>= 1) s += __shfl_xor(s, off, 64);
    float mean = s * (1.f / 64.f);
    float c = v - mean;
    float vv = c * c;
    for (int off = 32; off; off >>= 1) vv += __shfl_xor(vv, off, 64);
    float var = vv * (1.f / 64.f);
    out[(size_t)r * 64 + d] = c * rsqrtf(var + 1e-5f) * g[d] + b[d];
}

// ---------------- Final MLP: LDS-tiled 3-layer GEMM ----------------
#define MLP_STEP(ai, xi) {                                                        \
    ai.x = fmaf(xi.x, w0.x, fmaf(xi.y, w0.y, fmaf(xi.z, w0.z, fmaf(xi.w, w0.w, ai.x)))); \
    ai.y = fmaf(xi.x, w1.x, fmaf(xi.y, w1.y, fmaf(xi.z, w1.z, fmaf(xi.w, w1.w, ai.y)))); \
    ai.z = fmaf(xi.x, w2.x, fmaf(xi.y, w2.y, fmaf(xi.z, w2.z, fmaf(xi.w, w2.w, ai.z)))); \
    ai.w = fmaf(xi.x, w3.x, fmaf(xi.y, w3.y, fmaf(xi.z, w3.z, fmaf(xi.w, w3.w, ai.w)))); }

#define MLP_LAYER(B_)                                                             \
    a0 = z4; a1 = z4; a2 = z4; a3 = z4; a4 = z4; a5 = z4; a6 = z4; a7 = z4;       \
    _Pragma("unroll 4")                                                           \
    for (int k4 = 0; k4 < 32; ++k4) {                                             \
        float4 w0 = sW4[og][k4 ^ swz];                                            \
        float4 w1 = sW4[og + 32][k4 ^ swz];                                       \
        float4 w2 = sW4[og + 64][k4 ^ swz];                                       \
        float4 w3 = sW4[og + 96][k4 ^ swz];                                       \
        float4 x0 = sX4[pb + 0][k4], x1 = sX4[pb + 1][k4];                        \
        float4 x2 = sX4[pb + 2][k4], x3 = sX4[pb + 3][k4];                        \
        float4 x4 = sX4[pb + 4][k4], x5 = sX4[pb + 5][k4];                        \
        float4 x6 = sX4[pb + 6][k4], x7 = sX4[pb + 7][k4];                        \
        MLP_STEP(a0, x0) MLP_STEP(a1, x1) MLP_STEP(a2, x2) MLP_STEP(a3, x3)       \
        MLP_STEP(a4, x4) MLP_STEP(a5, x5) MLP_STEP(a6, x6) MLP_STEP(a7, x7)       \
    }                                                                             \
    {                                                                             \
        float bo0 = B_[og], bo1 = B_[og + 32], bo2 = B_[og + 64], bo3 = B_[og + 96]; \
        a0.x += bo0; a0.y += bo1; a0.z += bo2; a0.w += bo3;                       \
        a1.x += bo0; a1.y += bo1; a1.z += bo2; a1.w += bo3;                       \
        a2.x += bo0; a2.y += bo1; a2.z += bo2; a2.w += bo3;                       \
        a3.x += bo0; a3.y += bo1; a3.z += bo2; a3.w += bo3;                       \
        a4.x += bo0; a4.y += bo1; a4.z += bo2; a4.w += bo3;                       \
        a5.x += bo0; a5.y += bo1; a5.z += bo2; a5.w += bo3;                       \
        a6.x += bo0; a6.y += bo1; a6.z += bo2; a6.w += bo3;                       \
        a7.x += bo0; a7.y += bo1; a7.z += bo2; a7.w += bo3;                       \
    }

#define MLP_HWRITE(ai, i) {                                                       \
    float* hp_ = sXf + (size_t)(pb + (i)) * 128;                                  \
    hp_[og]      = ai.x > 0.f ? ai.x : 0.f;                                       \
    hp_[og + 32] = ai.y > 0.f ? ai.y : 0.f;                                       \
    hp_[og + 64] = ai.z > 0.f ? ai.z : 0.f;                                       \
    hp_[og + 96] = ai.w > 0.f ? ai.w : 0.f; }

#define MLP_WLOAD(Wg_) {                                                          \
    const float4* wsrc_ = (const float4*)(Wg_);                                   \
    _Pragma("unroll")                                                             \
    for (int u = 0; u < 16; ++u) {                                                \
        int f4i = u * 256 + t;                                                    \
        int o_ = f4i >> 5, k4_ = f4i & 31;                                        \
        sW4[o_][k4_ ^ (o_ & 7)] = wsrc_[f4i];                                     \
    } }

__global__ __launch_bounds__(256, 1)
void k_mlp(const float* __restrict__ px, const float* __restrict__ dx,
           const int* __restrict__ pairs,
           const float* __restrict__ W1, const float* __restrict__ b1,
           const float* __restrict__ W2, const float* __restrict__ b2,
           const float* __restrict__ W3, const float* __restrict__ b3,
           float* __restrict__ out) {
    __shared__ float4 sX4[64][32];         // 32 KB: x tile, then h1, then h2
    __shared__ float4 sW4[128][32];        // 64 KB: W1, then W2 (swizzled)
    float* sXf = (float*)sX4;
    int t = threadIdx.x;
    int base = blockIdx.x * 64;

    // gather X = concat(px[ip], dx[id]) for 64 pairs
    #pragma unroll
    for (int u = 0; u < 8; ++u) {
        int idx = u * 256 + t;
        int p = idx >> 5, c4 = idx & 31;
        int ip = pairs[(base + p) * 2], id = pairs[(base + p) * 2 + 1];
        float4 v = (c4 < 16) ? ((const float4*)px)[(size_t)ip * 16 + c4]
                             : ((const float4*)dx)[(size_t)id * 16 + (c4 - 16)];
        sX4[p][c4] = v;
    }
    MLP_WLOAD(W1)
    __syncthreads();

    int og = t & 31;                       // out group: o = og + 32j
    int pb = (t >> 5) * 8;                 // first of 8 pairs
    int swz = og & 7;                      // W k4-swizzle (32j keeps o&7 = og&7)
    float4 z4 = make_float4(0.f, 0.f, 0.f, 0.f);
    float4 a0, a1, a2, a3, a4, a5, a6, a7;

    MLP_LAYER(b1)                          // fc1 from X
    __syncthreads();                       // all fc1 reads done
    MLP_HWRITE(a0, 0) MLP_HWRITE(a1, 1) MLP_HWRITE(a2, 2) MLP_HWRITE(a3, 3)
    MLP_HWRITE(a4, 4) MLP_HWRITE(a5, 5) MLP_HWRITE(a6, 6) MLP_HWRITE(a7, 7)
    MLP_WLOAD(W2)
    __syncthreads();                       // h1 + W2 ready

    MLP_LAYER(b2)                          // fc2 from h1
    __syncthreads();                       // all fc2 reads done
    MLP_HWRITE(a0, 0) MLP_HWRITE(a1, 1) MLP_HWRITE(a2, 2) MLP_HWRITE(a3, 3)
    MLP_HWRITE(a4, 4) MLP_HWRITE(a5, 5) MLP_HWRITE(a6, 6) MLP_HWRITE(a7, 7)
    __syncthreads();                       // h2 ready

    // fc3: out[p] = b3 + h2[p] . W3   (4 threads per pair, shfl-reduce)
    {
        int p = t >> 2, qd = t & 3;
        const float4* w3 = (const float4*)W3;
        float sum = 0.f;
        #pragma unroll
        for (int u = 0; u < 8; ++u) {
            float4 h = sX4[p][qd * 8 + u];
            float4 w = w3[qd * 8 + u];
            sum += h.x * w.x + h.y * w.y + h.z * w.z + h.w * w.w;
        }
        sum += __shfl_xor(sum, 1, 64);
        sum += __shfl_xor(sum, 2, 64);
        if ((t & 3) == 0) out[base + p] = sum + b3[0];
    }
}

extern "C" void kernel_launch(void* const* d_in, const int* in_sizes, int n_in,
                              void* d_out, int out_size, void* d_ws, size_t ws_size,
                              hipStream_t stream) {
    const float* pfeat = (const float*)d_in[0];
    const float* padj  = (const float*)d_in[1];
    const float* dfeat = (const float*)d_in[2];
    const float* dadj  = (const float*)d_in[3];
    const int*   pairs = (const int*)d_in[4];
    const float* fc1W = (const float*)d_in[33];
    const float* fc1b = (const float*)d_in[34];
    const float* fc2W = (const float*)d_in[35];
    const float* fc2b = (const float*)d_in[36];
    const float* fc3W = (const float*)d_in[37];
    const float* fc3b = (const float*)d_in[38];

    float* ws = (float*)d_ws;
    float* buf_Wh   = ws;                              // 8*2048*8   = 131072
    float* buf_s1   = buf_Wh   + 8 * 2048 * 8;         // 16384
    float* buf_s2   = buf_s1   + 8 * 2048;             // 16384
    float* buf_gat  = buf_s2   + 8 * 2048;             // 131072
    float* buf_proj = buf_gat  + 2048 * 64;            // 131072
    float* buf_qkv  = buf_proj + 2048 * 64;            // 3145728
    float* buf_acc  = buf_qkv  + 24 * 2048 * 64;       // 131072
    float* buf_x    = buf_acc  + 2048 * 64;            // 131072
    float* buf_px   = buf_x    + 2048 * 64;            // 131072
    float* buf_dx   = buf_px   + 2048 * 64;            // 96000

    auto run_branch = [&](const float* feat, const float* adj, int N, int F,
                          void* const* w, float* xout) {
        const float* g1W = (const float*)w[0];
        const float* g1a = (const float*)w[1];
        const float* p1W = (const float*)w[2];
        const float* s1W = (const float*)w[3];
        const float* s1b = (const float*)w[4];
        const float* l1g = (const float*)w[5];
        const float* l1b = (const float*)w[6];
        const float* g2W = (const float*)w[7];
        const float* g2a = (const float*)w[8];
        const float* p2W = (const float*)w[9];
        const float* s2W = (const float*)w[10];
        const float* s2b = (const float*)w[11];
        const float* l2g = (const float*)w[12];
        const float* l2b = (const float*)w[13];

        int attnGrid = 64 * ((N + 31) / 32);   // bid: m=bid&7, h=(bid>>3)&7, rt=bid>>6

        // ---- layer 1 ----
        k_gat_wh<<<(64 * N + 255) / 256, 256, 0, stream>>>(feat, g1W, buf_Wh, N, F);
        k_gat_s<<<(8 * N + 255) / 256, 256, 0, stream>>>(buf_Wh, g1a, buf_s1, buf_s2, N);
        k_gat_attn<<<N, 256, 0, stream>>>(adj, buf_s1, buf_s2, buf_Wh, buf_gat, N);
        k_proj<<<(64 * N + 255) / 256, 256, 0, stream>>>(buf_gat, p1W, buf_proj, N);
        k_qkv<<<(1536 * N + 255) / 256, 256, 0, stream>>>(buf_proj, s1W, s1b, buf_qkv, N);
        hipMemsetAsync(buf_acc, 0, (size_t)N * 64 * sizeof(float), stream);
        k_attn<<<attnGrid, 256, 0, stream>>>(buf_qkv, buf_acc, N);
        k_ln<<<(N + 3) / 4, 256, 0, stream>>>(buf_acc, buf_proj, l1g, l1b, buf_x, N);
        // ---- layer 2 ----
        k_gat_wh<<<(64 * N + 255) / 256, 256, 0, stream>>>(buf_x, g2W, buf_Wh, N, EMB);
        k_gat_s<<<(8 * N + 255) / 256, 256, 0, stream>>>(buf_Wh, g2a, buf_s1, buf_s2, N);
        k_gat_attn<<<N, 256, 0, stream>>>(adj, buf_s1, buf_s2, buf_Wh, buf_gat, N);
        k_proj<<<(64 * N + 255) / 256, 256, 0, stream>>>(buf_gat, p2W, buf_proj, N);
        k_qkv<<<(1536 * N + 255) / 256, 256, 0, stream>>>(buf_proj, s2W, s2b, buf_qkv, N);
        hipMemsetAsync(buf_acc, 0, (size_t)N * 64 * sizeof(float), stream);
        k_attn<<<attnGrid, 256, 0, stream>>>(buf_qkv, buf_acc, N);
        k_ln<<<(N + 3) / 4, 256, 0, stream>>>(buf_acc, buf_proj, l2g, l2b, xout, N);
    };

    run_branch(pfeat, padj, NPROT, 512, d_in + 5, buf_px);
    run_branch(dfeat, dadj, NDRUG, 256, d_in + 19, buf_dx);

    k_mlp<<<NPAIR / 64, 256, 0, stream>>>(buf_px, buf_dx, pairs,
                                          fc1W, fc1b, fc2W, fc2b, fc3W, fc3b,
                                          (float*)d_out);
}

// Round 16
// 1154.915 us; speedup vs baseline: 5.1579x; 1.0380x over previous
//
#include <hip/hip_runtime.h>
#include <math.h>

#define NHID 8
#define NHEADS 8
#define EMB 64
#define NPROT 2048
#define NDRUG 1500
#define NPAIR 16384

typedef _Float16 h2 __attribute__((ext_vector_type(2)));
typedef float f4 __attribute__((ext_vector_type(4)));

// ---------------- GAT: Wh[h][n][o] = sum_f h[n,f] * W[h,f,o] ----------------
__global__ void k_gat_wh(const float* __restrict__ h, const float* __restrict__ W,
                         float* __restrict__ Wh, int N, int F) {
    int idx = blockIdx.x * 256 + threadIdx.x;       // flat (hh, n, o)
    int total = NHEADS * N * NHID;
    if (idx >= total) return;
    int o  = idx & 7;
    int n  = (idx >> 3) % N;
    int hh = idx / (N * 8);
    const float4* hp4 = (const float4*)(h + (size_t)n * F);
    const float* wp = W + (size_t)hh * F * 8 + o;
    float acc = 0.f;
    for (int f4i = 0; f4i < (F >> 2); ++f4i) {
        float4 hv = hp4[f4i];
        int fb = f4i * 32;                           // (f4*4)*8
        acc = fmaf(hv.x, wp[fb], fmaf(hv.y, wp[fb + 8],
              fmaf(hv.z, wp[fb + 16], fmaf(hv.w, wp[fb + 24], acc))));
    }
    Wh[idx] = acc;
}

// s1[h][n] = Wh[h][n][:] . a[h][:8];  s2 uses a[h][8:16]
__global__ void k_gat_s(const float* __restrict__ Wh, const float* __restrict__ a,
                        float* __restrict__ s1, float* __restrict__ s2, int N) {
    int idx = blockIdx.x * 256 + threadIdx.x;       // h*N + n
    if (idx >= NHEADS * N) return;
    int hh = idx / N;
    const float* wp = Wh + (size_t)idx * 8;
    const float* ap = a + hh * 16;
    float x1 = 0.f, x2 = 0.f;
    for (int o = 0; o < 8; ++o) { x1 += wp[o] * ap[o]; x2 += wp[o] * ap[8 + o]; }
    s1[idx] = x1; s2[idx] = x2;
}

// One block per row i. 8 concurrent head-groups of 32 lanes each.
__global__ void k_gat_attn(const float* __restrict__ adj, const float* __restrict__ s1,
                           const float* __restrict__ s2, const float* __restrict__ Wh,
                           float* __restrict__ out, int N) {
    __shared__ int nbr[2048];
    __shared__ int s_cnt;
    int i = blockIdx.x;
    int tid = threadIdx.x;
    if (tid == 0) s_cnt = 0;
    __syncthreads();
    const float* arow = adj + (size_t)i * N;
    for (int j = tid; j < N; j += 256)
        if (arow[j] > 0.f) { int p = atomicAdd(&s_cnt, 1); nbr[p] = j; }
    __syncthreads();
    int cnt = s_cnt;
    int g  = tid >> 5;          // head index 0..7
    int ln = tid & 31;          // lane within head-group
    float si = s1[g * N + i];
    const float* s2h = s2 + g * N;
    // pass 1: group max of leakyrelu(si + s2[j])
    float mx = -1e30f;
    for (int t = ln; t < cnt; t += 32) {
        float e = si + s2h[nbr[t]];
        e = e > 0.f ? e : 0.2f * e;
        mx = fmaxf(mx, e);
    }
    #pragma unroll
    for (int off = 16; off; off >>= 1) mx = fmaxf(mx, __shfl_xor(mx, off, 32));
    // pass 2: exp-sum + weighted accumulation of Wh rows
    float acc[8] = {0, 0, 0, 0, 0, 0, 0, 0};
    float lsum = 0.f;
    for (int t = ln; t < cnt; t += 32) {
        int j = nbr[t];
        float e = si + s2h[j];
        e = e > 0.f ? e : 0.2f * e;
        float p = __expf(e - mx);
        lsum += p;
        const float4* wp = (const float4*)(Wh + ((size_t)g * N + j) * 8);
        float4 w0 = wp[0], w1 = wp[1];
        acc[0] += p * w0.x; acc[1] += p * w0.y; acc[2] += p * w0.z; acc[3] += p * w0.w;
        acc[4] += p * w1.x; acc[5] += p * w1.y; acc[6] += p * w1.z; acc[7] += p * w1.w;
    }
    #pragma unroll
    for (int off = 16; off; off >>= 1) {
        lsum += __shfl_xor(lsum, off, 32);
        #pragma unroll
        for (int d = 0; d < 8; ++d) acc[d] += __shfl_xor(acc[d], off, 32);
    }
    if (ln == 0) {
        float inv = 1.f / lsum;
        #pragma unroll
        for (int d = 0; d < 8; ++d) {
            float r = acc[d] * inv;
            out[(size_t)i * 64 + g * 8 + d] = r > 0.f ? r : 0.f;   // relu
        }
    }
}

// out[n][o] = sum_d in[n][d] * W[o][d]   (x @ W.T, no bias)
__global__ void k_proj(const float* __restrict__ in, const float* __restrict__ W,
                       float* __restrict__ out, int N) {
    int idx = blockIdx.x * 256 + threadIdx.x;
    if (idx >= N * 64) return;
    int o = idx & 63, n = idx >> 6;
    const float* ip = in + (size_t)n * 64;
    const float* wp = W + (size_t)o * 64;
    float acc = 0.f;
    for (int d = 0; d < 64; ++d) acc += ip[d] * wp[d];
    out[idx] = acc;
}

// qkv layout: [sm][h][n][8]  (slice per (module,head) contiguous)
__global__ void k_qkv(const float* __restrict__ x, const float* __restrict__ W,
                      const float* __restrict__ b, float* __restrict__ qkv, int N) {
    int idx = blockIdx.x * 256 + threadIdx.x;
    int total = 24 * N * 64;
    if (idx >= total) return;
    int o = idx & 63;
    int n = (idx >> 6) % N;
    int sm = idx / (N * 64);
    const float4* xp4 = (const float4*)(x + (size_t)n * 64);
    const float4* wp4 = (const float4*)(W + ((size_t)sm * 64 + o) * 64);
    float acc = b[sm * 64 + o];
    #pragma unroll 4
    for (int d4 = 0; d4 < 16; ++d4) {
        float4 xv = xp4[d4], wv = wp4[d4];
        acc = fmaf(xv.x, wv.x, fmaf(xv.y, wv.y, fmaf(xv.z, wv.z, fmaf(xv.w, wv.w, acc))));
    }
    qkv[(size_t)sm * N * 64 + (size_t)(o >> 3) * N * 8 + (size_t)n * 8 + (o & 7)] = acc;
}

// ---------------- MHSA flash attention, hd=8, BARRIER-FREE ----------------
// Lane = j; wave owns 8 q-rows (wave-uniform). K_j/V_j live in the LANE's
// registers straight from global (L2-resident slice; m=bid&7 keeps the slice
// XCD-local). No LDS, no __syncthreads -> waves run free; the Round-15
// profile showed per-SIMD VALU issue ~25% purely from barrier rendezvous.
// fp16 QK via v_dot2, packed PV via v_pk_fma_f32, bare v_exp_f32.
#define QLOADH(qa, qb, qc, qd, r) { int row_ = row0 + (r); if (row_ >= N) row_ = 0; \
    const f4* qp_ = (const f4*)(qsl + (size_t)row_ * 8);                          \
    f4 a_ = qp_[0], b_ = qp_[1];                                                  \
    qa = h2{(_Float16)(a_.x * qs), (_Float16)(a_.y * qs)};                        \
    qb = h2{(_Float16)(a_.z * qs), (_Float16)(a_.w * qs)};                        \
    qc = h2{(_Float16)(b_.x * qs), (_Float16)(b_.y * qs)};                        \
    qd = h2{(_Float16)(b_.z * qs), (_Float16)(b_.w * qs)}; }

#define ROWSTEPH(qa, qb, qc, qd, ca, cb, lr) {                                    \
    float s_ = __builtin_amdgcn_fdot2(qa, kk0,                                    \
               __builtin_amdgcn_fdot2(qb, kk1,                                    \
               __builtin_amdgcn_fdot2(qc, kk2,                                    \
               __builtin_amdgcn_fdot2(qd, kk3, 0.f, false), false), false), false);\
    float p_ = __builtin_amdgcn_exp2f(s_); lr += p_;                              \
    f4 pv_ = {p_, p_, p_, p_};                                                    \
    ca = __builtin_elementwise_fma(pv_, vv0, ca);                                 \
    cb = __builtin_elementwise_fma(pv_, vv1, cb); }

#define TILEBODY {                                                                \
    h2 kk0 = h2{(_Float16)ka.x, (_Float16)ka.y};                                  \
    h2 kk1 = h2{(_Float16)ka.z, (_Float16)ka.w};                                  \
    h2 kk2 = h2{(_Float16)kb.x, (_Float16)kb.y};                                  \
    h2 kk3 = h2{(_Float16)kb.z, (_Float16)kb.w};                                  \
    ROWSTEPH(q0a, q0b, q0c, q0d, c0a, c0b, l0)                                    \
    ROWSTEPH(q1a, q1b, q1c, q1d, c1a, c1b, l1)                                    \
    ROWSTEPH(q2a, q2b, q2c, q2d, c2a, c2b, l2)                                    \
    ROWSTEPH(q3a, q3b, q3c, q3d, c3a, c3b, l3)                                    \
    ROWSTEPH(q4a, q4b, q4c, q4d, c4a, c4b, l4)                                    \
    ROWSTEPH(q5a, q5b, q5c, q5d, c5a, c5b, l5)                                    \
    ROWSTEPH(q6a, q6b, q6c, q6d, c6a, c6b, l6)                                    \
    ROWSTEPH(q7a, q7b, q7c, q7d, c7a, c7b, l7) }

#define BF3A(v) { v += __shfl_xor(v, 1, 64); v += __shfl_xor(v, 2, 64);           \
                  v += __shfl_xor(v, 4, 64); }

#define ROWOUT(ca, cb, lr, r) {                                                   \
    float ax_ = ca.x, ay_ = ca.y, az_ = ca.z, aw_ = ca.w;                         \
    float bx_ = cb.x, by_ = cb.y, bz_ = cb.z, bw_ = cb.w;                         \
    BF3A(ax_); BF3A(ay_); BF3A(az_); BF3A(aw_);                                   \
    BF3A(bx_); BF3A(by_); BF3A(bz_); BF3A(bw_); BF3A(lr);                         \
    int sel_ = ln & 7;                                                            \
    float t_ = (sel_ == 0) ? ax_ : (sel_ == 1) ? ay_ : (sel_ == 2) ? az_ :        \
               (sel_ == 3) ? aw_ : (sel_ == 4) ? bx_ : (sel_ == 5) ? by_ :        \
               (sel_ == 6) ? bz_ : bw_;                                           \
    t_ += __shfl_xor(t_, 8, 64); t_ += __shfl_xor(t_, 16, 64);                    \
    t_ += __shfl_xor(t_, 32, 64);                                                 \
    lr += __shfl_xor(lr, 8, 64); lr += __shfl_xor(lr, 16, 64);                    \
    lr += __shfl_xor(lr, 32, 64);                                                 \
    int row_ = row0 + (r);                                                        \
    if (ln < 8 && row_ < N)                                                       \
        atomicAdd(&accum[(size_t)row_ * 64 + hh * 8 + ln], t_ / (lr - phantom)); }

__global__ __launch_bounds__(256, 1)
void k_attn(const float* __restrict__ qkv, float* __restrict__ accum, int N) {
    int bid = blockIdx.x;
    int m  = bid & 7;                      // same m -> same XCD (L2 locality)
    int hh = (bid >> 3) & 7;
    int rt = bid >> 6;
    int wid = threadIdx.x >> 6, ln = threadIdx.x & 63;
    int row0 = rt * 32 + wid * 8;
    const float* qsl = qkv + (size_t)m        * N * 64 + (size_t)hh * N * 8;
    const float* ksl = qkv + (size_t)(8 + m)  * N * 64 + (size_t)hh * N * 8;
    const float* vsl = qkv + (size_t)(16 + m) * N * 64 + (size_t)hh * N * 8;

    const float qs = 0.35355339059327373f * 1.44269504088896341f;  // 1/sqrt(8)*log2(e)
    h2 q0a, q0b, q0c, q0d, q1a, q1b, q1c, q1d, q2a, q2b, q2c, q2d, q3a, q3b, q3c, q3d;
    h2 q4a, q4b, q4c, q4d, q5a, q5b, q5c, q5d, q6a, q6b, q6c, q6d, q7a, q7b, q7c, q7d;
    QLOADH(q0a, q0b, q0c, q0d, 0) QLOADH(q1a, q1b, q1c, q1d, 1)
    QLOADH(q2a, q2b, q2c, q2d, 2) QLOADH(q3a, q3b, q3c, q3d, 3)
    QLOADH(q4a, q4b, q4c, q4d, 4) QLOADH(q5a, q5b, q5c, q5d, 5)
    QLOADH(q6a, q6b, q6c, q6d, 6) QLOADH(q7a, q7b, q7c, q7d, 7)

    const float* kp = ksl + (size_t)ln * 8;    // this lane's K row walk
    const float* vp = vsl + (size_t)ln * 8;

    float l0 = 0.f, l1 = 0.f, l2 = 0.f, l3 = 0.f, l4 = 0.f, l5 = 0.f, l6 = 0.f, l7 = 0.f;
    f4 zf4 = {0.f, 0.f, 0.f, 0.f};
    f4 c0a = zf4, c0b = zf4, c1a = zf4, c1b = zf4, c2a = zf4, c2b = zf4, c3a = zf4, c3b = zf4;
    f4 c4a = zf4, c4b = zf4, c5a = zf4, c5b = zf4, c6a = zf4, c6b = zf4, c7a = zf4, c7b = zf4;

    int Tfull = N >> 6;                    // full 64-j tiles
    int rem = N & 63;
    for (int t = 0; t < Tfull; ++t) {
        f4 ka = *(const f4*)kp;
        f4 kb = *(const f4*)(kp + 4);
        f4 vv0 = *(const f4*)vp;
        f4 vv1 = *(const f4*)(vp + 4);
        kp += 512; vp += 512;              // next tile (64 j x 8 floats)
        TILEBODY
    }
    if (rem) {                             // tail tile: zero-fill invalid lanes
        bool ok = ln < rem;
        f4 ka = ok ? *(const f4*)kp : zf4;
        f4 kb = ok ? *(const f4*)(kp + 4) : zf4;
        f4 vv0 = ok ? *(const f4*)vp : zf4;
        f4 vv1 = ok ? *(const f4*)(vp + 4) : zf4;
        TILEBODY
    }

    float phantom = rem ? (float)(64 - rem) : 0.f;  // zero lanes give exp2(0)=1
    ROWOUT(c0a, c0b, l0, 0) ROWOUT(c1a, c1b, l1, 1)
    ROWOUT(c2a, c2b, l2, 2) ROWOUT(c3a, c3b, l3, 3)
    ROWOUT(c4a, c4b, l4, 4) ROWOUT(c5a, c5b, l5, 5)
    ROWOUT(c6a, c6b, l6, 6) ROWOUT(c7a, c7b, l7, 7)
}

// out = LN(acc + resid) * g + b ; one wave (64 lanes) per row
__global__ void k_ln(const float* __restrict__ acc, const float* __restrict__ resid,
                     const float* __restrict__ g, const float* __restrict__ b,
                     float* __restrict__ out, int N) {
    int r = blockIdx.x * 4 + (threadIdx.x >> 6);
    int d = threadIdx.x & 63;
    if (r >= N) return;
    float v = acc[(size_t)r * 64 + d] + resid[(size_t)r * 64 + d];
    float s = v;
    for (int off = 32; off; off >>= 1) s += __shfl_xor(s, off, 64);
    float mean = s * (1.f / 64.f);
    float c = v - mean;
    float vv = c * c;
    for (int off = 32; off; off >>= 1) vv += __shfl_xor(vv, off, 64);
    float var = vv * (1.f / 64.f);
    out[(size_t)r * 64 + d] = c * rsqrtf(var + 1e-5f) * g[d] + b[d];
}

// ---------------- Final MLP: LDS-tiled 3-layer GEMM ----------------
#define MLP_STEP(ai, xi) {                                                        \
    ai.x = fmaf(xi.x, w0.x, fmaf(xi.y, w0.y, fmaf(xi.z, w0.z, fmaf(xi.w, w0.w, ai.x)))); \
    ai.y = fmaf(xi.x, w1.x, fmaf(xi.y, w1.y, fmaf(xi.z, w1.z, fmaf(xi.w, w1.w, ai.y)))); \
    ai.z = fmaf(xi.x, w2.x, fmaf(xi.y, w2.y, fmaf(xi.z, w2.z, fmaf(xi.w, w2.w, ai.z)))); \
    ai.w = fmaf(xi.x, w3.x, fmaf(xi.y, w3.y, fmaf(xi.z, w3.z, fmaf(xi.w, w3.w, ai.w)))); }

#define MLP_LAYER(B_)                                                             \
    a0 = z4; a1 = z4; a2 = z4; a3 = z4; a4 = z4; a5 = z4; a6 = z4; a7 = z4;       \
    _Pragma("unroll 4")                                                           \
    for (int k4 = 0; k4 < 32; ++k4) {                                             \
        float4 w0 = sW4[og][k4 ^ swz];                                            \
        float4 w1 = sW4[og + 32][k4 ^ swz];                                       \
        float4 w2 = sW4[og + 64][k4 ^ swz];                                       \
        float4 w3 = sW4[og + 96][k4 ^ swz];                                       \
        float4 x0 = sX4[pb + 0][k4], x1 = sX4[pb + 1][k4];                        \
        float4 x2 = sX4[pb + 2][k4], x3 = sX4[pb + 3][k4];                        \
        float4 x4 = sX4[pb + 4][k4], x5 = sX4[pb + 5][k4];                        \
        float4 x6 = sX4[pb + 6][k4], x7 = sX4[pb + 7][k4];                        \
        MLP_STEP(a0, x0) MLP_STEP(a1, x1) MLP_STEP(a2, x2) MLP_STEP(a3, x3)       \
        MLP_STEP(a4, x4) MLP_STEP(a5, x5) MLP_STEP(a6, x6) MLP_STEP(a7, x7)       \
    }                                                                             \
    {                                                                             \
        float bo0 = B_[og], bo1 = B_[og + 32], bo2 = B_[og + 64], bo3 = B_[og + 96]; \
        a0.x += bo0; a0.y += bo1; a0.z += bo2; a0.w += bo3;                       \
        a1.x += bo0; a1.y += bo1; a1.z += bo2; a1.w += bo3;                       \
        a2.x += bo0; a2.y += bo1; a2.z += bo2; a2.w += bo3;                       \
        a3.x += bo0; a3.y += bo1; a3.z += bo2; a3.w += bo3;                       \
        a4.x += bo0; a4.y += bo1; a4.z += bo2; a4.w += bo3;                       \
        a5.x += bo0; a5.y += bo1; a5.z += bo2; a5.w += bo3;                       \
        a6.x += bo0; a6.y += bo1; a6.z += bo2; a6.w += bo3;                       \
        a7.x += bo0; a7.y += bo1; a7.z += bo2; a7.w += bo3;                       \
    }

#define MLP_HWRITE(ai, i) {                                                       \
    float* hp_ = sXf + (size_t)(pb + (i)) * 128;                                  \
    hp_[og]      = ai.x > 0.f ? ai.x : 0.f;                                       \
    hp_[og + 32] = ai.y > 0.f ? ai.y : 0.f;                                       \
    hp_[og + 64] = ai.z > 0.f ? ai.z : 0.f;                                       \
    hp_[og + 96] = ai.w > 0.f ? ai.w : 0.f; }

#define MLP_WLOAD(Wg_) {                                                          \
    const float4* wsrc_ = (const float4*)(Wg_);                                   \
    _Pragma("unroll")                                                             \
    for (int u = 0; u < 16; ++u) {                                                \
        int f4i = u * 256 + t;                                                    \
        int o_ = f4i >> 5, k4_ = f4i & 31;                                        \
        sW4[o_][k4_ ^ (o_ & 7)] = wsrc_[f4i];                                     \
    } }

__global__ __launch_bounds__(256, 1)
void k_mlp(const float* __restrict__ px, const float* __restrict__ dx,
           const int* __restrict__ pairs,
           const float* __restrict__ W1, const float* __restrict__ b1,
           const float* __restrict__ W2, const float* __restrict__ b2,
           const float* __restrict__ W3, const float* __restrict__ b3,
           float* __restrict__ out) {
    __shared__ float4 sX4[64][32];         // 32 KB: x tile, then h1, then h2
    __shared__ float4 sW4[128][32];        // 64 KB: W1, then W2 (swizzled)
    float* sXf = (float*)sX4;
    int t = threadIdx.x;
    int base = blockIdx.x * 64;

    // gather X = concat(px[ip], dx[id]) for 64 pairs
    #pragma unroll
    for (int u = 0; u < 8; ++u) {
        int idx = u * 256 + t;
        int p = idx >> 5, c4 = idx & 31;
        int ip = pairs[(base + p) * 2], id = pairs[(base + p) * 2 + 1];
        float4 v = (c4 < 16) ? ((const float4*)px)[(size_t)ip * 16 + c4]
                             : ((const float4*)dx)[(size_t)id * 16 + (c4 - 16)];
        sX4[p][c4] = v;
    }
    MLP_WLOAD(W1)
    __syncthreads();

    int og = t & 31;                       // out group: o = og + 32j
    int pb = (t >> 5) * 8;                 // first of 8 pairs
    int swz = og & 7;                      // W k4-swizzle (32j keeps o&7 = og&7)
    float4 z4 = make_float4(0.f, 0.f, 0.f, 0.f);
    float4 a0, a1, a2, a3, a4, a5, a6, a7;

    MLP_LAYER(b1)                          // fc1 from X
    __syncthreads();                       // all fc1 reads done
    MLP_HWRITE(a0, 0) MLP_HWRITE(a1, 1) MLP_HWRITE(a2, 2) MLP_HWRITE(a3, 3)
    MLP_HWRITE(a4, 4) MLP_HWRITE(a5, 5) MLP_HWRITE(a6, 6) MLP_HWRITE(a7, 7)
    MLP_WLOAD(W2)
    __syncthreads();                       // h1 + W2 ready

    MLP_LAYER(b2)                          // fc2 from h1
    __syncthreads();                       // all fc2 reads done
    MLP_HWRITE(a0, 0) MLP_HWRITE(a1, 1) MLP_HWRITE(a2, 2) MLP_HWRITE(a3, 3)
    MLP_HWRITE(a4, 4) MLP_HWRITE(a5, 5) MLP_HWRITE(a6, 6) MLP_HWRITE(a7, 7)
    __syncthreads();                       // h2 ready

    // fc3: out[p] = b3 + h2[p] . W3   (4 threads per pair, shfl-reduce)
    {
        int p = t >> 2, qd = t & 3;
        const float4* w3 = (const float4*)W3;
        float sum = 0.f;
        #pragma unroll
        for (int u = 0; u < 8; ++u) {
            float4 h = sX4[p][qd * 8 + u];
            float4 w = w3[qd * 8 + u];
            sum += h.x * w.x + h.y * w.y + h.z * w.z + h.w * w.w;
        }
        sum += __shfl_xor(sum, 1, 64);
        sum += __shfl_xor(sum, 2, 64);
        if ((t & 3) == 0) out[base + p] = sum + b3[0];
    }
}

extern "C" void kernel_launch(void* const* d_in, const int* in_sizes, int n_in,
                              void* d_out, int out_size, void* d_ws, size_t ws_size,
                              hipStream_t stream) {
    const float* pfeat = (const float*)d_in[0];
    const float* padj  = (const float*)d_in[1];
    const float* dfeat = (const float*)d_in[2];
    const float* dadj  = (const float*)d_in[3];
    const int*   pairs = (const int*)d_in[4];
    const float* fc1W = (const float*)d_in[33];
    const float* fc1b = (const float*)d_in[34];
    const float* fc2W = (const float*)d_in[35];
    const float* fc2b = (const float*)d_in[36];
    const float* fc3W = (const float*)d_in[37];
    const float* fc3b = (const float*)d_in[38];

    float* ws = (float*)d_ws;
    float* buf_Wh   = ws;                              // 8*2048*8   = 131072
    float* buf_s1   = buf_Wh   + 8 * 2048 * 8;         // 16384
    float* buf_s2   = buf_s1   + 8 * 2048;             // 16384
    float* buf_gat  = buf_s2   + 8 * 2048;             // 131072
    float* buf_proj = buf_gat  + 2048 * 64;            // 131072
    float* buf_qkv  = buf_proj + 2048 * 64;            // 3145728
    float* buf_acc  = buf_qkv  + 24 * 2048 * 64;       // 131072
    float* buf_x    = buf_acc  + 2048 * 64;            // 131072
    float* buf_px   = buf_x    + 2048 * 64;            // 131072
    float* buf_dx   = buf_px   + 2048 * 64;            // 96000

    auto run_branch = [&](const float* feat, const float* adj, int N, int F,
                          void* const* w, float* xout) {
        const float* g1W = (const float*)w[0];
        const float* g1a = (const float*)w[1];
        const float* p1W = (const float*)w[2];
        const float* s1W = (const float*)w[3];
        const float* s1b = (const float*)w[4];
        const float* l1g = (const float*)w[5];
        const float* l1b = (const float*)w[6];
        const float* g2W = (const float*)w[7];
        const float* g2a = (const float*)w[8];
        const float* p2W = (const float*)w[9];
        const float* s2W = (const float*)w[10];
        const float* s2b = (const float*)w[11];
        const float* l2g = (const float*)w[12];
        const float* l2b = (const float*)w[13];

        int attnGrid = 64 * ((N + 31) / 32);   // bid: m=bid&7, h=(bid>>3)&7, rt=bid>>6

        // ---- layer 1 ----
        k_gat_wh<<<(64 * N + 255) / 256, 256, 0, stream>>>(feat, g1W, buf_Wh, N, F);
        k_gat_s<<<(8 * N + 255) / 256, 256, 0, stream>>>(buf_Wh, g1a, buf_s1, buf_s2, N);
        k_gat_attn<<<N, 256, 0, stream>>>(adj, buf_s1, buf_s2, buf_Wh, buf_gat, N);
        k_proj<<<(64 * N + 255) / 256, 256, 0, stream>>>(buf_gat, p1W, buf_proj, N);
        k_qkv<<<(1536 * N + 255) / 256, 256, 0, stream>>>(buf_proj, s1W, s1b, buf_qkv, N);
        hipMemsetAsync(buf_acc, 0, (size_t)N * 64 * sizeof(float), stream);
        k_attn<<<attnGrid, 256, 0, stream>>>(buf_qkv, buf_acc, N);
        k_ln<<<(N + 3) / 4, 256, 0, stream>>>(buf_acc, buf_proj, l1g, l1b, buf_x, N);
        // ---- layer 2 ----
        k_gat_wh<<<(64 * N + 255) / 256, 256, 0, stream>>>(buf_x, g2W, buf_Wh, N, EMB);
        k_gat_s<<<(8 * N + 255) / 256, 256, 0, stream>>>(buf_Wh, g2a, buf_s1, buf_s2, N);
        k_gat_attn<<<N, 256, 0, stream>>>(adj, buf_s1, buf_s2, buf_Wh, buf_gat, N);
        k_proj<<<(64 * N + 255) / 256, 256, 0, stream>>>(buf_gat, p2W, buf_proj, N);
        k_qkv<<<(1536 * N + 255) / 256, 256, 0, stream>>>(buf_proj, s2W, s2b, buf_qkv, N);
        hipMemsetAsync(buf_acc, 0, (size_t)N * 64 * sizeof(float), stream);
        k_attn<<<attnGrid, 256, 0, stream>>>(buf_qkv, buf_acc, N);
        k_ln<<<(N + 3) / 4, 256, 0, stream>>>(buf_acc, buf_proj, l2g, l2b, xout, N);
    };

    run_branch(pfeat, padj, NPROT, 512, d_in + 5, buf_px);
    run_branch(dfeat, dadj, NDRUG, 256, d_in + 19, buf_dx);

    k_mlp<<<NPAIR / 64, 256, 0, stream>>>(buf_px, buf_dx, pairs,
                                          fc1W, fc1b, fc2W, fc2b, fc3W, fc3b,
                                          (float*)d_out);
}